// Round 7
// baseline (362.853 us; speedup 1.0000x reference)
//
#include <hip/hip_runtime.h>

#define NN 20000
#define EE 20000

typedef __attribute__((ext_vector_type(8))) short short8;
typedef __attribute__((ext_vector_type(4))) short short4v;
typedef __attribute__((ext_vector_type(4))) float f32x4;

// workspace layout (float indices)
#define WS_EF     0                         // edge_feat [E][64]
#define WS_TRANS  (WS_EF + EE*64)           // trans [E][3]
#define WS_CNTI   (WS_TRANS + EE*3)         // int cnt[N]
#define WS_OFF    (WS_CNTI + NN)            // int off[N+1]
#define WS_CUR    (WS_OFF + NN + 1)         // int cursor[N]
#define WS_EIDX   (WS_CUR + NN)             // int eidx[E]
#define WS_CORE_END (WS_EIDX + EE)
#define WS1S_ELEMS (4096*128)               // bf16 elems of swizzled 64*Ws1 (1 MB)

// LDS float offsets (edge kernel, 32-edge blocks)
#define OFF_SIN  0       // s_in [32][129]=4128 ; t1 [128][33]=4224 (same region)
#define OFF_E1   4224    // e1 [64 f][32 e] ; later ef            (2048)
#define OFF_G2   6272    // g f32 [64 i][32 e] ; later v          (2048)
#define OFF_GBF  8320    // g bf16 swizzled [32 e][128 B]         (1024)
#define SM_FLOATS 9344   // 37.4 KB

__device__ __forceinline__ float siluf(float x) {
    return x * (1.0f / (1.0f + __expf(-x)));
}
__device__ __forceinline__ unsigned short f2bf(float f) {
    union { float f; unsigned u; } v; v.f = f;
    return (unsigned short)((v.u + 0x7FFF + ((v.u >> 16) & 1)) >> 16);
}

// ---------- CSR build ----------
__global__ void hist_csr(const int* __restrict__ ei, int* __restrict__ cnt) {
    const int e = blockIdx.x * 256 + threadIdx.x;
    if (e < EE) atomicAdd(&cnt[ei[e]], 1);
}

__global__ void scan_csr(const int* __restrict__ cnt, int* __restrict__ off,
                         int* __restrict__ cursor) {
    const int t = threadIdx.x;        // 1024 threads, 20 items each
    __shared__ int ps[1024];
    int loc[20];
    int s = 0;
    const int base = t * 20;
    #pragma unroll
    for (int k = 0; k < 20; ++k) {
        const int i = base + k;
        const int c = (i < NN) ? cnt[i] : 0;
        loc[k] = s; s += c;
    }
    ps[t] = s;
    __syncthreads();
    for (int d = 1; d < 1024; d <<= 1) {
        const int v = (t >= d) ? ps[t - d] : 0;
        __syncthreads();
        ps[t] += v;
        __syncthreads();
    }
    const int excl = ps[t] - s;
    #pragma unroll
    for (int k = 0; k < 20; ++k) {
        const int i = base + k;
        if (i < NN) { const int v = excl + loc[k]; off[i] = v; cursor[i] = v; }
    }
    if (t == 1023) off[NN] = ps[1023];
}

__global__ void fill_csr(const int* __restrict__ ei, int* __restrict__ cursor,
                         int* __restrict__ eidx) {
    const int e = blockIdx.x * 256 + threadIdx.x;
    if (e < EE) {
        const int p = atomicAdd(&cursor[ei[e]], 1);
        eidx[p] = e;
    }
}

// out[((s*8+tn)*64 + l)*8 + u] = bf16(64*Ws1[(s*32 + 8*(l>>4) + u)][tn*16 + (l&15)])
__global__ void swz_ws1(const float* __restrict__ Ws1, unsigned short* __restrict__ out) {
    const int tid = blockIdx.x * 256 + threadIdx.x;   // 65536 threads
    const int l = tid & 63, fid = tid >> 6;
    const int s = fid >> 3, tn = fid & 7;
    const int krow = s * 32 + 8 * (l >> 4);
    const int ncol = tn * 16 + (l & 15);
    short8 frag;
    #pragma unroll
    for (int u = 0; u < 8; ++u)
        frag[u] = (short)f2bf(64.0f * Ws1[(krow + u) * 128 + ncol]);
    *(short8*)&out[(size_t)tid * 8] = frag;
}

__global__ __launch_bounds__(512, 4)
void egcl_edge_kernel(const float* __restrict__ h, const float* __restrict__ coord,
                      const int* __restrict__ ei,
                      const float* __restrict__ We1, const float* __restrict__ be1,
                      const float* __restrict__ We2, const float* __restrict__ be2,
                      const unsigned short* __restrict__ Ws1s, const float* __restrict__ bs1,
                      const float* __restrict__ Ws2, const float* __restrict__ bs2,
                      const float* __restrict__ Wc1, const float* __restrict__ bc1,
                      const float* __restrict__ Wc2,
                      float* __restrict__ ef_out, float* __restrict__ trans_out)
{
    __shared__ __attribute__((aligned(16))) float sm[SM_FLOATS];
    __shared__ int s_row[32], s_col[32];
    __shared__ float s_cd[96], s_rad[32];

    const int t = threadIdx.x;
    const int e0 = blockIdx.x * 32;   // 625 * 32 == 20000 exactly

    if (t < 32) {
        const int r = ei[e0 + t], c = ei[EE + e0 + t];
        s_row[t] = r; s_col[t] = c;
        const float dx = coord[r*3+0] - coord[c*3+0];
        const float dy = coord[r*3+1] - coord[c*3+1];
        const float dz = coord[r*3+2] - coord[c*3+2];
        s_cd[t] = dx; s_cd[32+t] = dy; s_cd[64+t] = dz;
        s_rad[t] = dx*dx + dy*dy + dz*dz;
    }
    __syncthreads();

    // MLP mapping: e = t>>4 (edge 0..31), fg = t&15 (4 feats each)
    const int e = t >> 4, fg = t & 15;

    // gather: s_in[e][129] = [h[row](64), h[col](64), radial]
    {
        const int r = s_row[e], c = s_col[e];
        const float* src = (fg < 8) ? &h[(size_t)r*64 + fg*8]
                                    : &h[(size_t)c*64 + (fg-8)*8];
        float* dst = &sm[OFF_SIN + e*129 + fg*8];
        #pragma unroll
        for (int u = 0; u < 8; ++u) dst[u] = src[u];
        if (fg == 0) sm[OFF_SIN + e*129 + 128] = s_rad[e];
    }
    __syncthreads();

    // e1 = silu(in @ We1 + be1) -> OFF_E1 [feat][32e]
    {
        float acc[4];
        #pragma unroll
        for (int u = 0; u < 4; ++u) acc[u] = be1[fg*4 + u];
        const float* din = &sm[OFF_SIN + e*129];
        #pragma unroll 4
        for (int q = 0; q < 129; ++q) {
            const float x = din[q];
            const float* wr = &We1[q*64 + fg*4];
            #pragma unroll
            for (int u = 0; u < 4; ++u) acc[u] = fmaf(x, wr[u], acc[u]);
        }
        #pragma unroll
        for (int u = 0; u < 4; ++u) sm[OFF_E1 + (fg*4+u)*32 + e] = siluf(acc[u]);
    }
    __syncthreads();

    // g = silu(e1 @ We2 + be2) -> f32 [i][32e] at OFF_G2, bf16 swizzled at OFF_GBF
    {
        float acc[4];
        #pragma unroll
        for (int u = 0; u < 4; ++u) acc[u] = be2[fg*4 + u];
        #pragma unroll 4
        for (int q = 0; q < 64; ++q) {
            const float x = sm[OFF_E1 + q*32 + e];
            const float* wr = &We2[q*64 + fg*4];
            #pragma unroll
            for (int u = 0; u < 4; ++u) acc[u] = fmaf(x, wr[u], acc[u]);
        }
        short4v bf;
        #pragma unroll
        for (int u = 0; u < 4; ++u) {
            const float s = siluf(acc[u]);
            sm[OFF_G2 + (fg*4+u)*32 + e] = s;
            bf[u] = (short)f2bf(s);
        }
        // chunk c = fg>>1 holds feats c*8..c*8+8; this thread writes half (fg&1)
        *(short4v*)((char*)sm + OFF_GBF*4 + e*128 + (((fg>>1) ^ (e&7))*16) + (fg&1)*8) = bf;
    }
    __syncthreads();

    // ---- SO3 GEMM: acc[e,k] = sum_i g[e,i] * (g_bf16[e,:] @ 64*Ws1_i[:,k])
    // Wave w owns cols [w*16,+16). B goes L2 -> registers directly (no LDS, no
    // barriers, no async hazards). Two 8-step register banks ping-pong; the
    // compiler's dependency-tracked counted vmcnt does the pipelining.
    const int l = t & 63, w = t >> 6;
    const int kg = l >> 4;

    short8 A[2][2];
    #pragma unroll
    for (int et = 0; et < 2; ++et) {
        const int er = et*16 + (l & 15);
        #pragma unroll
        for (int kh = 0; kh < 2; ++kh)
            A[et][kh] = *(const short8*)((const char*)sm + OFF_GBF*4 + er*128 +
                                         (((kh*4 + kg) ^ (er & 7)) * 16));
    }

    float accv[2][4];
    #pragma unroll
    for (int et = 0; et < 2; ++et)
        #pragma unroll
        for (int r = 0; r < 4; ++r) accv[et][r] = 0.0f;

    const short8* Bp = (const short8*)Ws1s;   // frag for step s: Bp[(s*8 + w)*64 + l]
    short8 pA[8], pB[8];

#define LOADBANK(P, BASE) { \
    _Pragma("unroll") \
    for (int j = 0; j < 8; ++j) P[j] = Bp[(((BASE)+j)*8 + w)*64 + l]; \
    __builtin_amdgcn_sched_barrier(0); }
#define USEBANK(P, BASE) { \
    _Pragma("unroll") \
    for (int k = 0; k < 4; ++k) { \
        f32x4 c0 = __builtin_amdgcn_mfma_f32_16x16x32_bf16(A[0][0], P[2*k],   (f32x4){0.f,0.f,0.f,0.f}, 0, 0, 0); \
        f32x4 c1 = __builtin_amdgcn_mfma_f32_16x16x32_bf16(A[1][0], P[2*k],   (f32x4){0.f,0.f,0.f,0.f}, 0, 0, 0); \
        c0 = __builtin_amdgcn_mfma_f32_16x16x32_bf16(A[0][1], P[2*k+1], c0, 0, 0, 0); \
        c1 = __builtin_amdgcn_mfma_f32_16x16x32_bf16(A[1][1], P[2*k+1], c1, 0, 0, 0); \
        const int i_ = (BASE)/2 + k; \
        const f32x4 g0 = *(const f32x4*)&sm[OFF_G2 + i_*32 + (kg << 2)]; \
        const f32x4 g1 = *(const f32x4*)&sm[OFF_G2 + i_*32 + 16 + (kg << 2)]; \
        _Pragma("unroll") \
        for (int r = 0; r < 4; ++r) { \
            accv[0][r] = fmaf(g0[r], c0[r], accv[0][r]); \
            accv[1][r] = fmaf(g1[r], c1[r], accv[1][r]); \
        } \
    } }

    LOADBANK(pA, 0)
    LOADBANK(pB, 8)
    #pragma unroll 1
    for (int m = 0; m < 7; ++m) {
        USEBANK(pA, 16*m)
        LOADBANK(pA, 16*m + 16)
        USEBANK(pB, 16*m + 8)
        LOADBANK(pB, 16*m + 24)
    }
    USEBANK(pA, 112)
    USEBANK(pB, 120)
#undef LOADBANK
#undef USEBANK

    // t1 = relu(acc + bs1) -> OFF_SIN region, [col][33] (wave-private cols; s_in dead)
    {
        const int col = w*16 + (l & 15);
        const float bk = bs1[col];
        #pragma unroll
        for (int et = 0; et < 2; ++et)
            #pragma unroll
            for (int r = 0; r < 4; ++r)
                sm[OFF_SIN + col*33 + et*16 + (kg << 2) + r] = fmaxf(accv[et][r] + bk, 0.0f);
    }
    __syncthreads();

    // edge_feat = t1 @ Ws2 + bs2 -> ef [o][32e] at OFF_E1
    {
        float a2[4];
        #pragma unroll
        for (int u = 0; u < 4; ++u) a2[u] = bs2[fg*4 + u];
        #pragma unroll 4
        for (int k = 0; k < 128; ++k) {
            const float x = sm[OFF_SIN + k*33 + e];
            const float* wr = &Ws2[k*64 + fg*4];
            #pragma unroll
            for (int u = 0; u < 4; ++u) a2[u] = fmaf(x, wr[u], a2[u]);
        }
        #pragma unroll
        for (int u = 0; u < 4; ++u) sm[OFF_E1 + (fg*4+u)*32 + e] = a2[u];
    }
    __syncthreads();

    // v = silu(ef @ Wc1 + bc1) -> OFF_G2 [f][32e]
    {
        float a3[4];
        #pragma unroll
        for (int u = 0; u < 4; ++u) a3[u] = bc1[fg*4 + u];
        #pragma unroll 4
        for (int q = 0; q < 64; ++q) {
            const float x = sm[OFF_E1 + q*32 + e];
            const float* wr = &Wc1[q*64 + fg*4];
            #pragma unroll
            for (int u = 0; u < 4; ++u) a3[u] = fmaf(x, wr[u], a3[u]);
        }
        #pragma unroll
        for (int u = 0; u < 4; ++u) sm[OFF_G2 + (fg*4+u)*32 + e] = siluf(a3[u]);
    }
    __syncthreads();

    // coord weight -> dense trans write
    if (t < 32) {
        float cw = 0.0f;
        #pragma unroll 4
        for (int f = 0; f < 64; ++f) cw = fmaf(sm[OFF_G2 + f*32 + t], Wc2[f], cw);
        const int eid = e0 + t;
        trans_out[eid*3 + 0] = s_cd[t]    * cw;
        trans_out[eid*3 + 1] = s_cd[32+t] * cw;
        trans_out[eid*3 + 2] = s_cd[64+t] * cw;
    }
    // dense edge_feat write (coalesced)
    {
        float* dst = &ef_out[(size_t)(e0 + e)*64 + fg*4];
        #pragma unroll
        for (int u = 0; u < 4; ++u) dst[u] = sm[OFF_E1 + (fg*4+u)*32 + e];
    }
}

__global__ __launch_bounds__(256, 3)
void egcl_node_kernel(const float* __restrict__ h, const float* __restrict__ coord,
                      const int* __restrict__ ei,
                      const float* __restrict__ Wn1, const float* __restrict__ bn1,
                      const float* __restrict__ Wn2, const float* __restrict__ bn2,
                      const float* __restrict__ ef, const float* __restrict__ trans,
                      const int* __restrict__ off, const int* __restrict__ eidx,
                      float* __restrict__ out)
{
    __shared__ float s_m[131*32];
    __shared__ float s_z[64*32];
    __shared__ float s_w2[64*67];   // Wn2 staged (fixes stride-268B uncoalesced reads)
    const int t = threadIdx.x;
    const int n0 = blockIdx.x * 32;
    const int n = t >> 3, og = t & 7;
    const int gn = n0 + n;

    for (int idx = t; idx < 64*67; idx += 256) s_w2[idx] = Wn2[idx];

    // h -> s_m rows 0..63
    {
        const float* hp = &h[(size_t)gn*64 + og*8];
        #pragma unroll
        for (int u = 0; u < 8; ++u) s_m[(og*8+u)*32 + n] = hp[u];
    }
    // CSR gather: agg (rows 67..130) + num/cnt -> coord_out
    {
        const int o0 = off[gn], o1 = off[gn + 1];
        float acc[8];
        #pragma unroll
        for (int u = 0; u < 8; ++u) acc[u] = 0.0f;
        float nx = 0.0f, ny = 0.0f, nz = 0.0f;
        for (int j = o0; j < o1; ++j) {
            const int e2 = eidx[j];
            const float* ep = &ef[(size_t)e2*64 + og*8];
            #pragma unroll
            for (int u = 0; u < 8; ++u) acc[u] += ep[u];
            if (og == 0) {
                nx += trans[e2*3 + 0];
                ny += trans[e2*3 + 1];
                nz += trans[e2*3 + 2];
            }
        }
        #pragma unroll
        for (int u = 0; u < 8; ++u) s_m[(67+og*8+u)*32 + n] = acc[u];
        if (og == 0) {
            const float cnt = fmaxf((float)(o1 - o0), 1.0f);
            out[NN*67 + gn*3 + 0] = coord[gn*3 + 0] + nx / cnt;
            out[NN*67 + gn*3 + 1] = coord[gn*3 + 1] + ny / cnt;
            out[NN*67 + gn*3 + 2] = coord[gn*3 + 2] + nz / cnt;
        }
    }
    // rel for node n comes from edge n (E == N quirk)
    if (t < 32) {
        const int nn2 = n0 + t;
        const int r = ei[nn2], c = ei[EE + nn2];
        const float dx = coord[r*3+0] - coord[c*3+0];
        const float dy = coord[r*3+1] - coord[c*3+1];
        const float dz = coord[r*3+2] - coord[c*3+2];
        const float inv = 1.0f / (sqrtf(dx*dx + dy*dy + dz*dz) + 1e-8f);
        s_m[64*32 + t] = dx*inv;
        s_m[65*32 + t] = dy*inv;
        s_m[66*32 + t] = dz*inv;
    }
    __syncthreads();

    // z = silu(m @ Wn1 + bn1)
    {
        float acc[8];
        #pragma unroll
        for (int u = 0; u < 8; ++u) acc[u] = bn1[og*8 + u];
        #pragma unroll 4
        for (int q = 0; q < 131; ++q) {
            const float x = s_m[q*32 + n];
            const float* wr = &Wn1[q*64 + og*8];
            #pragma unroll
            for (int u = 0; u < 8; ++u) acc[u] = fmaf(x, wr[u], acc[u]);
        }
        #pragma unroll
        for (int u = 0; u < 8; ++u) s_z[(og*8+u)*32 + n] = siluf(acc[u]);
    }
    __syncthreads();

    // h_out = h_pos + z @ Wn2 + bn2   (h_pos == m[0:67])
    {
        for (int o = og; o < 67; o += 8) {
            float a = s_m[o*32 + n] + bn2[o];
            #pragma unroll 4
            for (int k = 0; k < 64; ++k)
                a = fmaf(s_z[k*32 + n], s_w2[k*67 + o], a);
            out[(size_t)gn*67 + o] = a;
        }
    }
}

extern "C" void kernel_launch(void* const* d_in, const int* in_sizes, int n_in,
                              void* d_out, int out_size, void* d_ws, size_t ws_size,
                              hipStream_t stream)
{
    (void)in_sizes; (void)n_in; (void)out_size;
    const float* h     = (const float*)d_in[0];
    const float* coord = (const float*)d_in[1];
    const int*   ei    = (const int*)d_in[2];
    const float* We1   = (const float*)d_in[3];
    const float* be1   = (const float*)d_in[4];
    const float* We2   = (const float*)d_in[5];
    const float* be2   = (const float*)d_in[6];
    const float* Ws1   = (const float*)d_in[7];
    const float* bs1   = (const float*)d_in[8];
    const float* Ws2   = (const float*)d_in[9];
    const float* bs2   = (const float*)d_in[10];
    const float* Wc1   = (const float*)d_in[11];
    const float* bc1   = (const float*)d_in[12];
    const float* Wc2   = (const float*)d_in[13];
    const float* Wn1   = (const float*)d_in[14];
    const float* bn1   = (const float*)d_in[15];
    const float* Wn2   = (const float*)d_in[16];
    const float* bn2   = (const float*)d_in[17];
    float* ws  = (float*)d_ws;
    float* out = (float*)d_out;

    float* ef    = ws + WS_EF;
    float* trans = ws + WS_TRANS;
    int* cnti = (int*)(ws + WS_CNTI);
    int* off  = (int*)(ws + WS_OFF);
    int* cur  = (int*)(ws + WS_CUR);
    int* eidx = (int*)(ws + WS_EIDX);

    const size_t need_all = (size_t)WS_CORE_END * sizeof(float) + (size_t)WS1S_ELEMS * 2;
    unsigned short* ws1s = (ws_size >= need_all) ? (unsigned short*)(ws + WS_CORE_END)
                                                 : (unsigned short*)d_out;  // node kernel rewrites d_out afterwards

    hipMemsetAsync((void*)cnti, 0, (size_t)NN * sizeof(int), stream);
    hist_csr<<<(EE + 255)/256, 256, 0, stream>>>(ei, cnti);
    scan_csr<<<1, 1024, 0, stream>>>(cnti, off, cur);
    fill_csr<<<(EE + 255)/256, 256, 0, stream>>>(ei, cur, eidx);
    swz_ws1<<<256, 256, 0, stream>>>(Ws1, ws1s);
    egcl_edge_kernel<<<EE/32, 512, 0, stream>>>(h, coord, ei, We1, be1, We2, be2,
                                                ws1s, bs1, Ws2, bs2, Wc1, bc1, Wc2,
                                                ef, trans);
    egcl_node_kernel<<<NN/32, 256, 0, stream>>>(h, coord, ei, Wn1, bn1, Wn2, bn2,
                                                ef, trans, off, eidx, out);
}

// Round 8
// 198.229 us; speedup vs baseline: 1.8305x; 1.8305x over previous
//
#include <hip/hip_runtime.h>

#define NN 20000
#define EE 20000

typedef __attribute__((ext_vector_type(8))) short short8;
typedef __attribute__((ext_vector_type(4))) short short4v;
typedef __attribute__((ext_vector_type(4))) float f32x4;

// workspace layout (float indices)
#define WS_EF     0                         // edge_feat [E][64]
#define WS_TRANS  (WS_EF + EE*64)           // trans [E][3]
#define WS_CNTI   (WS_TRANS + EE*3)         // int cnt[N]
#define WS_OFF    (WS_CNTI + NN)            // int off[N+1]
#define WS_CUR    (WS_OFF + NN + 1)         // int cursor[N]
#define WS_EIDX   (WS_CUR + NN)             // int eidx[E]
#define WS_CORE_END (WS_EIDX + EE)
#define WS1S_ELEMS (4096*128)               // bf16 elems of swizzled 64*Ws1 (1 MB)

// LDS float offsets (edge kernel, 32-edge blocks)
#define OFF_SIN  0       // s_in [32][129]=4128 ; t1 [128][33]=4224 (same region)
#define OFF_E1   4224    // e1 [64 f][32 e] ; later ef            (2048)
#define OFF_G2   6272    // g f32 [64 i][32 e] ; later v          (2048)
#define OFF_GBF  8320    // g bf16 swizzled [32 e][128 B]         (1024)
#define SM_FLOATS 9344   // 37.4 KB

__device__ __forceinline__ float siluf(float x) {
    return x * (1.0f / (1.0f + __expf(-x)));
}
__device__ __forceinline__ unsigned short f2bf(float f) {
    union { float f; unsigned u; } v; v.f = f;
    return (unsigned short)((v.u + 0x7FFF + ((v.u >> 16) & 1)) >> 16);
}

// ---------- CSR build ----------
__global__ void hist_csr(const int* __restrict__ ei, int* __restrict__ cnt) {
    const int e = blockIdx.x * 256 + threadIdx.x;
    if (e < EE) atomicAdd(&cnt[ei[e]], 1);
}

__global__ void scan_csr(const int* __restrict__ cnt, int* __restrict__ off,
                         int* __restrict__ cursor) {
    const int t = threadIdx.x;        // 1024 threads, 20 items each
    __shared__ int ps[1024];
    int loc[20];
    int s = 0;
    const int base = t * 20;
    #pragma unroll
    for (int k = 0; k < 20; ++k) {
        const int i = base + k;
        const int c = (i < NN) ? cnt[i] : 0;
        loc[k] = s; s += c;
    }
    ps[t] = s;
    __syncthreads();
    for (int d = 1; d < 1024; d <<= 1) {
        const int v = (t >= d) ? ps[t - d] : 0;
        __syncthreads();
        ps[t] += v;
        __syncthreads();
    }
    const int excl = ps[t] - s;
    #pragma unroll
    for (int k = 0; k < 20; ++k) {
        const int i = base + k;
        if (i < NN) { const int v = excl + loc[k]; off[i] = v; cursor[i] = v; }
    }
    if (t == 1023) off[NN] = ps[1023];
}

__global__ void fill_csr(const int* __restrict__ ei, int* __restrict__ cursor,
                         int* __restrict__ eidx) {
    const int e = blockIdx.x * 256 + threadIdx.x;
    if (e < EE) {
        const int p = atomicAdd(&cursor[ei[e]], 1);
        eidx[p] = e;
    }
}

// out[((s*8+tn)*64 + l)*8 + u] = bf16(64*Ws1[(s*32 + 8*(l>>4) + u)][tn*16 + (l&15)])
__global__ void swz_ws1(const float* __restrict__ Ws1, unsigned short* __restrict__ out) {
    const int tid = blockIdx.x * 256 + threadIdx.x;   // 65536 threads
    const int l = tid & 63, fid = tid >> 6;
    const int s = fid >> 3, tn = fid & 7;
    const int krow = s * 32 + 8 * (l >> 4);
    const int ncol = tn * 16 + (l & 15);
    short8 frag;
    #pragma unroll
    for (int u = 0; u < 8; ++u)
        frag[u] = (short)f2bf(64.0f * Ws1[(krow + u) * 128 + ncol]);
    *(short8*)&out[(size_t)tid * 8] = frag;
}

// NOTE __launch_bounds__(512, 2): arg2 is MIN WAVES PER EU. 512-thr block = 2
// waves/EU, so "2" = 1 block min => VGPR cap 128. Round 7 used "4" => cap 64,
// which spilled the 64-VGPR B-register banks to scratch (485 MB of HBM writes).
__global__ __launch_bounds__(512, 2)
void egcl_edge_kernel(const float* __restrict__ h, const float* __restrict__ coord,
                      const int* __restrict__ ei,
                      const float* __restrict__ We1, const float* __restrict__ be1,
                      const float* __restrict__ We2, const float* __restrict__ be2,
                      const unsigned short* __restrict__ Ws1s, const float* __restrict__ bs1,
                      const float* __restrict__ Ws2, const float* __restrict__ bs2,
                      const float* __restrict__ Wc1, const float* __restrict__ bc1,
                      const float* __restrict__ Wc2,
                      float* __restrict__ ef_out, float* __restrict__ trans_out)
{
    __shared__ __attribute__((aligned(16))) float sm[SM_FLOATS];
    __shared__ int s_row[32], s_col[32];
    __shared__ float s_cd[96], s_rad[32];

    const int t = threadIdx.x;
    const int e0 = blockIdx.x * 32;   // 625 * 32 == 20000 exactly

    if (t < 32) {
        const int r = ei[e0 + t], c = ei[EE + e0 + t];
        s_row[t] = r; s_col[t] = c;
        const float dx = coord[r*3+0] - coord[c*3+0];
        const float dy = coord[r*3+1] - coord[c*3+1];
        const float dz = coord[r*3+2] - coord[c*3+2];
        s_cd[t] = dx; s_cd[32+t] = dy; s_cd[64+t] = dz;
        s_rad[t] = dx*dx + dy*dy + dz*dz;
    }
    __syncthreads();

    // MLP mapping: e = t>>4 (edge 0..31), fg = t&15 (4 feats each)
    const int e = t >> 4, fg = t & 15;

    // gather: s_in[e][129] = [h[row](64), h[col](64), radial]
    {
        const int r = s_row[e], c = s_col[e];
        const float* src = (fg < 8) ? &h[(size_t)r*64 + fg*8]
                                    : &h[(size_t)c*64 + (fg-8)*8];
        float* dst = &sm[OFF_SIN + e*129 + fg*8];
        #pragma unroll
        for (int u = 0; u < 8; ++u) dst[u] = src[u];
        if (fg == 0) sm[OFF_SIN + e*129 + 128] = s_rad[e];
    }
    __syncthreads();

    // e1 = silu(in @ We1 + be1) -> OFF_E1 [feat][32e]
    {
        float acc[4];
        #pragma unroll
        for (int u = 0; u < 4; ++u) acc[u] = be1[fg*4 + u];
        const float* din = &sm[OFF_SIN + e*129];
        #pragma unroll 4
        for (int q = 0; q < 129; ++q) {
            const float x = din[q];
            const float* wr = &We1[q*64 + fg*4];
            #pragma unroll
            for (int u = 0; u < 4; ++u) acc[u] = fmaf(x, wr[u], acc[u]);
        }
        #pragma unroll
        for (int u = 0; u < 4; ++u) sm[OFF_E1 + (fg*4+u)*32 + e] = siluf(acc[u]);
    }
    __syncthreads();

    // g = silu(e1 @ We2 + be2) -> f32 [i][32e] at OFF_G2, bf16 swizzled at OFF_GBF
    {
        float acc[4];
        #pragma unroll
        for (int u = 0; u < 4; ++u) acc[u] = be2[fg*4 + u];
        #pragma unroll 4
        for (int q = 0; q < 64; ++q) {
            const float x = sm[OFF_E1 + q*32 + e];
            const float* wr = &We2[q*64 + fg*4];
            #pragma unroll
            for (int u = 0; u < 4; ++u) acc[u] = fmaf(x, wr[u], acc[u]);
        }
        short4v bf;
        #pragma unroll
        for (int u = 0; u < 4; ++u) {
            const float s = siluf(acc[u]);
            sm[OFF_G2 + (fg*4+u)*32 + e] = s;
            bf[u] = (short)f2bf(s);
        }
        // chunk c = fg>>1 holds feats c*8..c*8+8; this thread writes half (fg&1)
        *(short4v*)((char*)sm + OFF_GBF*4 + e*128 + (((fg>>1) ^ (e&7))*16) + (fg&1)*8) = bf;
    }
    __syncthreads();

    // ---- SO3 GEMM: acc[e,k] = sum_i g[e,i] * (g_bf16[e,:] @ 64*Ws1_i[:,k])
    // Wave w owns cols [w*16,+16). B goes L2 -> registers directly (no LDS, no
    // barriers, no async hazards). Two 8-step register banks ping-pong; the
    // compiler's dependency-tracked counted vmcnt does the pipelining.
    const int l = t & 63, w = t >> 6;
    const int kg = l >> 4;

    short8 A[2][2];
    #pragma unroll
    for (int et = 0; et < 2; ++et) {
        const int er = et*16 + (l & 15);
        #pragma unroll
        for (int kh = 0; kh < 2; ++kh)
            A[et][kh] = *(const short8*)((const char*)sm + OFF_GBF*4 + er*128 +
                                         (((kh*4 + kg) ^ (er & 7)) * 16));
    }

    float accv[2][4];
    #pragma unroll
    for (int et = 0; et < 2; ++et)
        #pragma unroll
        for (int r = 0; r < 4; ++r) accv[et][r] = 0.0f;

    const short8* Bp = (const short8*)Ws1s;   // frag for step s: Bp[(s*8 + w)*64 + l]
    short8 pA[8], pB[8];

#define LOADBANK(P, BASE) { \
    _Pragma("unroll") \
    for (int j = 0; j < 8; ++j) P[j] = Bp[(((BASE)+j)*8 + w)*64 + l]; \
    __builtin_amdgcn_sched_barrier(0); }
#define USEBANK(P, BASE) { \
    _Pragma("unroll") \
    for (int k = 0; k < 4; ++k) { \
        f32x4 c0 = __builtin_amdgcn_mfma_f32_16x16x32_bf16(A[0][0], P[2*k],   (f32x4){0.f,0.f,0.f,0.f}, 0, 0, 0); \
        f32x4 c1 = __builtin_amdgcn_mfma_f32_16x16x32_bf16(A[1][0], P[2*k],   (f32x4){0.f,0.f,0.f,0.f}, 0, 0, 0); \
        c0 = __builtin_amdgcn_mfma_f32_16x16x32_bf16(A[0][1], P[2*k+1], c0, 0, 0, 0); \
        c1 = __builtin_amdgcn_mfma_f32_16x16x32_bf16(A[1][1], P[2*k+1], c1, 0, 0, 0); \
        const int i_ = (BASE)/2 + k; \
        const f32x4 g0 = *(const f32x4*)&sm[OFF_G2 + i_*32 + (kg << 2)]; \
        const f32x4 g1 = *(const f32x4*)&sm[OFF_G2 + i_*32 + 16 + (kg << 2)]; \
        _Pragma("unroll") \
        for (int r = 0; r < 4; ++r) { \
            accv[0][r] = fmaf(g0[r], c0[r], accv[0][r]); \
            accv[1][r] = fmaf(g1[r], c1[r], accv[1][r]); \
        } \
    } }

    LOADBANK(pA, 0)
    LOADBANK(pB, 8)
    #pragma unroll 1
    for (int m = 0; m < 7; ++m) {
        USEBANK(pA, 16*m)
        LOADBANK(pA, 16*m + 16)
        USEBANK(pB, 16*m + 8)
        LOADBANK(pB, 16*m + 24)
    }
    USEBANK(pA, 112)
    USEBANK(pB, 120)
#undef LOADBANK
#undef USEBANK

    // t1 = relu(acc + bs1) -> OFF_SIN region, [col][33] (wave-private cols; s_in dead)
    {
        const int col = w*16 + (l & 15);
        const float bk = bs1[col];
        #pragma unroll
        for (int et = 0; et < 2; ++et)
            #pragma unroll
            for (int r = 0; r < 4; ++r)
                sm[OFF_SIN + col*33 + et*16 + (kg << 2) + r] = fmaxf(accv[et][r] + bk, 0.0f);
    }
    __syncthreads();

    // edge_feat = t1 @ Ws2 + bs2 -> ef [o][32e] at OFF_E1
    {
        float a2[4];
        #pragma unroll
        for (int u = 0; u < 4; ++u) a2[u] = bs2[fg*4 + u];
        #pragma unroll 4
        for (int k = 0; k < 128; ++k) {
            const float x = sm[OFF_SIN + k*33 + e];
            const float* wr = &Ws2[k*64 + fg*4];
            #pragma unroll
            for (int u = 0; u < 4; ++u) a2[u] = fmaf(x, wr[u], a2[u]);
        }
        #pragma unroll
        for (int u = 0; u < 4; ++u) sm[OFF_E1 + (fg*4+u)*32 + e] = a2[u];
    }
    __syncthreads();

    // v = silu(ef @ Wc1 + bc1) -> OFF_G2 [f][32e]
    {
        float a3[4];
        #pragma unroll
        for (int u = 0; u < 4; ++u) a3[u] = bc1[fg*4 + u];
        #pragma unroll 4
        for (int q = 0; q < 64; ++q) {
            const float x = sm[OFF_E1 + q*32 + e];
            const float* wr = &Wc1[q*64 + fg*4];
            #pragma unroll
            for (int u = 0; u < 4; ++u) a3[u] = fmaf(x, wr[u], a3[u]);
        }
        #pragma unroll
        for (int u = 0; u < 4; ++u) sm[OFF_G2 + (fg*4+u)*32 + e] = siluf(a3[u]);
    }
    __syncthreads();

    // coord weight -> dense trans write
    if (t < 32) {
        float cw = 0.0f;
        #pragma unroll 4
        for (int f = 0; f < 64; ++f) cw = fmaf(sm[OFF_G2 + f*32 + t], Wc2[f], cw);
        const int eid = e0 + t;
        trans_out[eid*3 + 0] = s_cd[t]    * cw;
        trans_out[eid*3 + 1] = s_cd[32+t] * cw;
        trans_out[eid*3 + 2] = s_cd[64+t] * cw;
    }
    // dense edge_feat write (coalesced)
    {
        float* dst = &ef_out[(size_t)(e0 + e)*64 + fg*4];
        #pragma unroll
        for (int u = 0; u < 4; ++u) dst[u] = sm[OFF_E1 + (fg*4+u)*32 + e];
    }
}

__global__ __launch_bounds__(256, 3)
void egcl_node_kernel(const float* __restrict__ h, const float* __restrict__ coord,
                      const int* __restrict__ ei,
                      const float* __restrict__ Wn1, const float* __restrict__ bn1,
                      const float* __restrict__ Wn2, const float* __restrict__ bn2,
                      const float* __restrict__ ef, const float* __restrict__ trans,
                      const int* __restrict__ off, const int* __restrict__ eidx,
                      float* __restrict__ out)
{
    __shared__ float s_m[131*32];
    __shared__ float s_z[64*32];
    __shared__ float s_w2[64*67];   // Wn2 staged (fixes stride-268B uncoalesced reads)
    const int t = threadIdx.x;
    const int n0 = blockIdx.x * 32;
    const int n = t >> 3, og = t & 7;
    const int gn = n0 + n;

    for (int idx = t; idx < 64*67; idx += 256) s_w2[idx] = Wn2[idx];

    // h -> s_m rows 0..63
    {
        const float* hp = &h[(size_t)gn*64 + og*8];
        #pragma unroll
        for (int u = 0; u < 8; ++u) s_m[(og*8+u)*32 + n] = hp[u];
    }
    // CSR gather: agg (rows 67..130) + num/cnt -> coord_out
    {
        const int o0 = off[gn], o1 = off[gn + 1];
        float acc[8];
        #pragma unroll
        for (int u = 0; u < 8; ++u) acc[u] = 0.0f;
        float nx = 0.0f, ny = 0.0f, nz = 0.0f;
        for (int j = o0; j < o1; ++j) {
            const int e2 = eidx[j];
            const float* ep = &ef[(size_t)e2*64 + og*8];
            #pragma unroll
            for (int u = 0; u < 8; ++u) acc[u] += ep[u];
            if (og == 0) {
                nx += trans[e2*3 + 0];
                ny += trans[e2*3 + 1];
                nz += trans[e2*3 + 2];
            }
        }
        #pragma unroll
        for (int u = 0; u < 8; ++u) s_m[(67+og*8+u)*32 + n] = acc[u];
        if (og == 0) {
            const float cnt = fmaxf((float)(o1 - o0), 1.0f);
            out[NN*67 + gn*3 + 0] = coord[gn*3 + 0] + nx / cnt;
            out[NN*67 + gn*3 + 1] = coord[gn*3 + 1] + ny / cnt;
            out[NN*67 + gn*3 + 2] = coord[gn*3 + 2] + nz / cnt;
        }
    }
    // rel for node n comes from edge n (E == N quirk)
    if (t < 32) {
        const int nn2 = n0 + t;
        const int r = ei[nn2], c = ei[EE + nn2];
        const float dx = coord[r*3+0] - coord[c*3+0];
        const float dy = coord[r*3+1] - coord[c*3+1];
        const float dz = coord[r*3+2] - coord[c*3+2];
        const float inv = 1.0f / (sqrtf(dx*dx + dy*dy + dz*dz) + 1e-8f);
        s_m[64*32 + t] = dx*inv;
        s_m[65*32 + t] = dy*inv;
        s_m[66*32 + t] = dz*inv;
    }
    __syncthreads();

    // z = silu(m @ Wn1 + bn1)
    {
        float acc[8];
        #pragma unroll
        for (int u = 0; u < 8; ++u) acc[u] = bn1[og*8 + u];
        #pragma unroll 4
        for (int q = 0; q < 131; ++q) {
            const float x = s_m[q*32 + n];
            const float* wr = &Wn1[q*64 + og*8];
            #pragma unroll
            for (int u = 0; u < 8; ++u) acc[u] = fmaf(x, wr[u], acc[u]);
        }
        #pragma unroll
        for (int u = 0; u < 8; ++u) s_z[(og*8+u)*32 + n] = siluf(acc[u]);
    }
    __syncthreads();

    // h_out = h_pos + z @ Wn2 + bn2   (h_pos == m[0:67])
    {
        for (int o = og; o < 67; o += 8) {
            float a = s_m[o*32 + n] + bn2[o];
            #pragma unroll 4
            for (int k = 0; k < 64; ++k)
                a = fmaf(s_z[k*32 + n], s_w2[k*67 + o], a);
            out[(size_t)gn*67 + o] = a;
        }
    }
}

extern "C" void kernel_launch(void* const* d_in, const int* in_sizes, int n_in,
                              void* d_out, int out_size, void* d_ws, size_t ws_size,
                              hipStream_t stream)
{
    (void)in_sizes; (void)n_in; (void)out_size;
    const float* h     = (const float*)d_in[0];
    const float* coord = (const float*)d_in[1];
    const int*   ei    = (const int*)d_in[2];
    const float* We1   = (const float*)d_in[3];
    const float* be1   = (const float*)d_in[4];
    const float* We2   = (const float*)d_in[5];
    const float* be2   = (const float*)d_in[6];
    const float* Ws1   = (const float*)d_in[7];
    const float* bs1   = (const float*)d_in[8];
    const float* Ws2   = (const float*)d_in[9];
    const float* bs2   = (const float*)d_in[10];
    const float* Wc1   = (const float*)d_in[11];
    const float* bc1   = (const float*)d_in[12];
    const float* Wc2   = (const float*)d_in[13];
    const float* Wn1   = (const float*)d_in[14];
    const float* bn1   = (const float*)d_in[15];
    const float* Wn2   = (const float*)d_in[16];
    const float* bn2   = (const float*)d_in[17];
    float* ws  = (float*)d_ws;
    float* out = (float*)d_out;

    float* ef    = ws + WS_EF;
    float* trans = ws + WS_TRANS;
    int* cnti = (int*)(ws + WS_CNTI);
    int* off  = (int*)(ws + WS_OFF);
    int* cur  = (int*)(ws + WS_CUR);
    int* eidx = (int*)(ws + WS_EIDX);

    const size_t need_all = (size_t)WS_CORE_END * sizeof(float) + (size_t)WS1S_ELEMS * 2;
    unsigned short* ws1s = (ws_size >= need_all) ? (unsigned short*)(ws + WS_CORE_END)
                                                 : (unsigned short*)d_out;  // node kernel rewrites d_out afterwards

    hipMemsetAsync((void*)cnti, 0, (size_t)NN * sizeof(int), stream);
    hist_csr<<<(EE + 255)/256, 256, 0, stream>>>(ei, cnti);
    scan_csr<<<1, 1024, 0, stream>>>(cnti, off, cur);
    fill_csr<<<(EE + 255)/256, 256, 0, stream>>>(ei, cur, eidx);
    swz_ws1<<<256, 256, 0, stream>>>(Ws1, ws1s);
    egcl_edge_kernel<<<EE/32, 512, 0, stream>>>(h, coord, ei, We1, be1, We2, be2,
                                                ws1s, bs1, Ws2, bs2, Wc1, bc1, Wc2,
                                                ef, trans);
    egcl_node_kernel<<<NN/32, 256, 0, stream>>>(h, coord, ei, Wn1, bn1, Wn2, bn2,
                                                ef, trans, off, eidx, out);
}

// Round 9
// 148.336 us; speedup vs baseline: 2.4462x; 1.3363x over previous
//
#include <hip/hip_runtime.h>

#define NN 20000
#define EE 20000

typedef __attribute__((ext_vector_type(8))) short short8;
typedef __attribute__((ext_vector_type(4))) short short4v;
typedef __attribute__((ext_vector_type(4))) float f32x4;

// workspace layout (float indices)
#define WS_EF     0                         // edge_feat [E][64]
#define WS_TRANS  (WS_EF + EE*64)           // trans [E][3]
#define WS_CNTI   (WS_TRANS + EE*3)         // int cnt[N]
#define WS_OFF    (WS_CNTI + NN)            // int off[N+1]
#define WS_CUR    (WS_OFF + NN + 1)         // int cursor[N]
#define WS_EIDX   (WS_CUR + NN)             // int eidx[E]
#define WS_CORE_END (WS_EIDX + EE)
#define WS1S_ELEMS (4096*128)               // bf16 elems of swizzled 64*Ws1 (1 MB)

// LDS float offsets (edge kernel, 32-edge blocks)
#define OFF_SIN  0       // s_in [32][132]=4224 ; t1 [128][33]=4224 (same region)
#define OFF_E1   4224    // e1 [64 f][32 e] ; later ef            (2048)
#define OFF_G2   6272    // g f32 [64 i][32 e] ; later v          (2048)
#define OFF_GBF  8320    // g bf16 swizzled [32 e][128 B]         (1024)
#define OFF_W    9344    // staged weights, max 8256 (We1)
#define SM_FLOATS 17600  // 70.4 KB -> 2 blocks/CU (VGPR-bound anyway)

__device__ __forceinline__ float siluf(float x) {
    return x * (1.0f / (1.0f + __expf(-x)));
}
__device__ __forceinline__ unsigned short f2bf(float f) {
    union { float f; unsigned u; } v; v.f = f;
    return (unsigned short)((v.u + 0x7FFF + ((v.u >> 16) & 1)) >> 16);
}

// ---------- CSR build ----------
__global__ void hist_csr(const int* __restrict__ ei, int* __restrict__ cnt) {
    const int e = blockIdx.x * 256 + threadIdx.x;
    if (e < EE) atomicAdd(&cnt[ei[e]], 1);
}

__global__ void scan_csr(const int* __restrict__ cnt, int* __restrict__ off,
                         int* __restrict__ cursor) {
    const int t = threadIdx.x;        // 1024 threads, 20 items each
    __shared__ int ps[1024];
    int loc[20];
    int s = 0;
    const int base = t * 20;
    #pragma unroll
    for (int k = 0; k < 20; ++k) {
        const int i = base + k;
        const int c = (i < NN) ? cnt[i] : 0;
        loc[k] = s; s += c;
    }
    ps[t] = s;
    __syncthreads();
    for (int d = 1; d < 1024; d <<= 1) {
        const int v = (t >= d) ? ps[t - d] : 0;
        __syncthreads();
        ps[t] += v;
        __syncthreads();
    }
    const int excl = ps[t] - s;
    #pragma unroll
    for (int k = 0; k < 20; ++k) {
        const int i = base + k;
        if (i < NN) { const int v = excl + loc[k]; off[i] = v; cursor[i] = v; }
    }
    if (t == 1023) off[NN] = ps[1023];
}

__global__ void fill_csr(const int* __restrict__ ei, int* __restrict__ cursor,
                         int* __restrict__ eidx) {
    const int e = blockIdx.x * 256 + threadIdx.x;
    if (e < EE) {
        const int p = atomicAdd(&cursor[ei[e]], 1);
        eidx[p] = e;
    }
}

// out[((s*8+tn)*64 + l)*8 + u] = bf16(64*Ws1[(s*32 + 8*(l>>4) + u)][tn*16 + (l&15)])
__global__ void swz_ws1(const float* __restrict__ Ws1, unsigned short* __restrict__ out) {
    const int tid = blockIdx.x * 256 + threadIdx.x;   // 65536 threads
    const int l = tid & 63, fid = tid >> 6;
    const int s = fid >> 3, tn = fid & 7;
    const int krow = s * 32 + 8 * (l >> 4);
    const int ncol = tn * 16 + (l & 15);
    short8 frag;
    #pragma unroll
    for (int u = 0; u < 8; ++u)
        frag[u] = (short)f2bf(64.0f * Ws1[(krow + u) * 128 + ncol]);
    *(short8*)&out[(size_t)tid * 8] = frag;
}

// __launch_bounds__(512, 2): arg2 = min waves/EU; 512-thr block = 2 waves/EU
// => VGPR cap 128 (fits the ~110-reg GEMM working set; "4" would cap at 64 and spill).
__global__ __launch_bounds__(512, 2)
void egcl_edge_kernel(const float* __restrict__ h, const float* __restrict__ coord,
                      const int* __restrict__ ei,
                      const float* __restrict__ We1, const float* __restrict__ be1,
                      const float* __restrict__ We2, const float* __restrict__ be2,
                      const unsigned short* __restrict__ Ws1s, const float* __restrict__ bs1,
                      const float* __restrict__ Ws2, const float* __restrict__ bs2,
                      const float* __restrict__ Wc1, const float* __restrict__ bc1,
                      const float* __restrict__ Wc2,
                      float* __restrict__ ef_out, float* __restrict__ trans_out)
{
    __shared__ __attribute__((aligned(16))) float sm[SM_FLOATS];
    __shared__ int s_row[32], s_col[32];
    __shared__ float s_cd[96], s_rad[32];

    const int t = threadIdx.x;
    const int e0 = blockIdx.x * 32;   // 625 * 32 == 20000 exactly

    // cooperative weight stage: global -> LDS, coalesced f32x4
#define STAGEW(SRC, NFLOATS) { \
    for (int i = t*4; i < (NFLOATS); i += 2048) \
        *(f32x4*)&sm[OFF_W + i] = *(const f32x4*)&(SRC)[i]; }

    if (t < 32) {
        const int r = ei[e0 + t], c = ei[EE + e0 + t];
        s_row[t] = r; s_col[t] = c;
        const float dx = coord[r*3+0] - coord[c*3+0];
        const float dy = coord[r*3+1] - coord[c*3+1];
        const float dz = coord[r*3+2] - coord[c*3+2];
        s_cd[t] = dx; s_cd[32+t] = dy; s_cd[64+t] = dz;
        s_rad[t] = dx*dx + dy*dy + dz*dz;
    }
    STAGEW(We1, 8256)            // overlaps with row/col setup
    __syncthreads();

    // MLP mapping: e = t>>4 (edge 0..31), fg = t&15 (4 feats each)
    const int e = t >> 4, fg = t & 15;

    // gather: s_in[e][132] = [h[row](64), h[col](64), radial@128]
    {
        const int r = s_row[e], c = s_col[e];
        const float* src = (fg < 8) ? &h[(size_t)r*64 + fg*8]
                                    : &h[(size_t)c*64 + (fg-8)*8];
        const f32x4 v0 = *(const f32x4*)&src[0];
        const f32x4 v1 = *(const f32x4*)&src[4];
        float* dst = &sm[OFF_SIN + e*132 + fg*8];   // 132 stride => 16B aligned
        *(f32x4*)&dst[0] = v0;
        *(f32x4*)&dst[4] = v1;
        if (fg == 0) sm[OFF_SIN + e*132 + 128] = s_rad[e];
    }
    __syncthreads();

    // e1 = silu(in @ We1 + be1) -> OFF_E1 [feat][32e]   (weights from LDS)
    {
        float acc[4];
        #pragma unroll
        for (int u = 0; u < 4; ++u) acc[u] = be1[fg*4 + u];
        const float* din = &sm[OFF_SIN + e*132];
        for (int q = 0; q < 129; ++q) {
            const float x = din[q];
            const f32x4 wv = *(const f32x4*)&sm[OFF_W + q*64 + fg*4];
            #pragma unroll
            for (int u = 0; u < 4; ++u) acc[u] = fmaf(x, wv[u], acc[u]);
        }
        #pragma unroll
        for (int u = 0; u < 4; ++u) sm[OFF_E1 + (fg*4+u)*32 + e] = siluf(acc[u]);
    }
    __syncthreads();

    STAGEW(We2, 4096)
    __syncthreads();

    // g = silu(e1 @ We2 + be2) -> f32 [i][32e] at OFF_G2, bf16 swizzled at OFF_GBF
    {
        float acc[4];
        #pragma unroll
        for (int u = 0; u < 4; ++u) acc[u] = be2[fg*4 + u];
        for (int q = 0; q < 64; ++q) {
            const float x = sm[OFF_E1 + q*32 + e];
            const f32x4 wv = *(const f32x4*)&sm[OFF_W + q*64 + fg*4];
            #pragma unroll
            for (int u = 0; u < 4; ++u) acc[u] = fmaf(x, wv[u], acc[u]);
        }
        short4v bf;
        #pragma unroll
        for (int u = 0; u < 4; ++u) {
            const float s = siluf(acc[u]);
            sm[OFF_G2 + (fg*4+u)*32 + e] = s;
            bf[u] = (short)f2bf(s);
        }
        *(short4v*)((char*)sm + OFF_GBF*4 + e*128 + (((fg>>1) ^ (e&7))*16) + (fg&1)*8) = bf;
    }
    __syncthreads();

    // stage Ws2 now: its global-load latency hides under the GEMM below
    STAGEW(Ws2, 8192)

    // ---- SO3 GEMM: acc[e,k] = sum_i g[e,i] * (g_bf16[e,:] @ 64*Ws1_i[:,k])
    // Wave w owns cols [w*16,+16). B: L2 -> registers, two 8-step banks ping-pong,
    // compiler-counted vmcnt, zero barriers. (R8-proven, VGPR 108, no spill.)
    const int l = t & 63, w = t >> 6;
    const int kg = l >> 4;

    short8 A[2][2];
    #pragma unroll
    for (int et = 0; et < 2; ++et) {
        const int er = et*16 + (l & 15);
        #pragma unroll
        for (int kh = 0; kh < 2; ++kh)
            A[et][kh] = *(const short8*)((const char*)sm + OFF_GBF*4 + er*128 +
                                         (((kh*4 + kg) ^ (er & 7)) * 16));
    }

    float accv[2][4];
    #pragma unroll
    for (int et = 0; et < 2; ++et)
        #pragma unroll
        for (int r = 0; r < 4; ++r) accv[et][r] = 0.0f;

    const short8* Bp = (const short8*)Ws1s;   // frag for step s: Bp[(s*8 + w)*64 + l]
    short8 pA[8], pB[8];

#define LOADBANK(P, BASE) { \
    _Pragma("unroll") \
    for (int j = 0; j < 8; ++j) P[j] = Bp[(((BASE)+j)*8 + w)*64 + l]; \
    __builtin_amdgcn_sched_barrier(0); }
#define USEBANK(P, BASE) { \
    _Pragma("unroll") \
    for (int k = 0; k < 4; ++k) { \
        f32x4 c0 = __builtin_amdgcn_mfma_f32_16x16x32_bf16(A[0][0], P[2*k],   (f32x4){0.f,0.f,0.f,0.f}, 0, 0, 0); \
        f32x4 c1 = __builtin_amdgcn_mfma_f32_16x16x32_bf16(A[1][0], P[2*k],   (f32x4){0.f,0.f,0.f,0.f}, 0, 0, 0); \
        c0 = __builtin_amdgcn_mfma_f32_16x16x32_bf16(A[0][1], P[2*k+1], c0, 0, 0, 0); \
        c1 = __builtin_amdgcn_mfma_f32_16x16x32_bf16(A[1][1], P[2*k+1], c1, 0, 0, 0); \
        const int i_ = (BASE)/2 + k; \
        const f32x4 g0 = *(const f32x4*)&sm[OFF_G2 + i_*32 + (kg << 2)]; \
        const f32x4 g1 = *(const f32x4*)&sm[OFF_G2 + i_*32 + 16 + (kg << 2)]; \
        _Pragma("unroll") \
        for (int r = 0; r < 4; ++r) { \
            accv[0][r] = fmaf(g0[r], c0[r], accv[0][r]); \
            accv[1][r] = fmaf(g1[r], c1[r], accv[1][r]); \
        } \
    } }

    LOADBANK(pA, 0)
    LOADBANK(pB, 8)
    #pragma unroll 1
    for (int m = 0; m < 7; ++m) {
        USEBANK(pA, 16*m)
        LOADBANK(pA, 16*m + 16)
        USEBANK(pB, 16*m + 8)
        LOADBANK(pB, 16*m + 24)
    }
    USEBANK(pA, 112)
    USEBANK(pB, 120)
#undef LOADBANK
#undef USEBANK

    // t1 = relu(acc + bs1) -> OFF_SIN region, [col][33] (wave-private cols; s_in dead)
    {
        const int col = w*16 + (l & 15);
        const float bk = bs1[col];
        #pragma unroll
        for (int et = 0; et < 2; ++et)
            #pragma unroll
            for (int r = 0; r < 4; ++r)
                sm[OFF_SIN + col*33 + et*16 + (kg << 2) + r] = fmaxf(accv[et][r] + bk, 0.0f);
    }
    __syncthreads();   // t1 visible + Ws2 staged

    // edge_feat = t1 @ Ws2 + bs2 -> ef [o][32e] at OFF_E1
    {
        float a2[4];
        #pragma unroll
        for (int u = 0; u < 4; ++u) a2[u] = bs2[fg*4 + u];
        for (int k = 0; k < 128; ++k) {
            const float x = sm[OFF_SIN + k*33 + e];
            const f32x4 wv = *(const f32x4*)&sm[OFF_W + k*64 + fg*4];
            #pragma unroll
            for (int u = 0; u < 4; ++u) a2[u] = fmaf(x, wv[u], a2[u]);
        }
        #pragma unroll
        for (int u = 0; u < 4; ++u) sm[OFF_E1 + (fg*4+u)*32 + e] = a2[u];
    }
    __syncthreads();

    STAGEW(Wc1, 4096)
    if (t < 64) sm[OFF_W + 4096 + t] = Wc2[t];
    __syncthreads();

    // v = silu(ef @ Wc1 + bc1) -> OFF_G2 [f][32e]
    {
        float a3[4];
        #pragma unroll
        for (int u = 0; u < 4; ++u) a3[u] = bc1[fg*4 + u];
        for (int q = 0; q < 64; ++q) {
            const float x = sm[OFF_E1 + q*32 + e];
            const f32x4 wv = *(const f32x4*)&sm[OFF_W + q*64 + fg*4];
            #pragma unroll
            for (int u = 0; u < 4; ++u) a3[u] = fmaf(x, wv[u], a3[u]);
        }
        #pragma unroll
        for (int u = 0; u < 4; ++u) sm[OFF_G2 + (fg*4+u)*32 + e] = siluf(a3[u]);
    }
    __syncthreads();

    // coord weight -> dense trans write
    if (t < 32) {
        float cw = 0.0f;
        for (int f = 0; f < 64; ++f) cw = fmaf(sm[OFF_G2 + f*32 + t], sm[OFF_W + 4096 + f], cw);
        const int eid = e0 + t;
        trans_out[eid*3 + 0] = s_cd[t]    * cw;
        trans_out[eid*3 + 1] = s_cd[32+t] * cw;
        trans_out[eid*3 + 2] = s_cd[64+t] * cw;
    }
    // dense edge_feat write (coalesced)
    {
        float* dst = &ef_out[(size_t)(e0 + e)*64 + fg*4];
        #pragma unroll
        for (int u = 0; u < 4; ++u) dst[u] = sm[OFF_E1 + (fg*4+u)*32 + e];
    }
#undef STAGEW
}

__global__ __launch_bounds__(256, 2)
void egcl_node_kernel(const float* __restrict__ h, const float* __restrict__ coord,
                      const int* __restrict__ ei,
                      const float* __restrict__ Wn1, const float* __restrict__ bn1,
                      const float* __restrict__ Wn2, const float* __restrict__ bn2,
                      const float* __restrict__ ef, const float* __restrict__ trans,
                      const int* __restrict__ off, const int* __restrict__ eidx,
                      float* __restrict__ out)
{
    __shared__ float s_m[131*32];
    __shared__ float s_z[64*32];
    __shared__ float s_w[131*64];   // Wn1 staged (8384), then Wn2 (4288)
    const int t = threadIdx.x;
    const int n0 = blockIdx.x * 32;
    const int n = t >> 3, og = t & 7;
    const int gn = n0 + n;

    for (int i = t*4; i < 131*64; i += 1024)
        *(f32x4*)&s_w[i] = *(const f32x4*)&Wn1[i];

    // h -> s_m rows 0..63
    {
        const float* hp = &h[(size_t)gn*64 + og*8];
        const f32x4 v0 = *(const f32x4*)&hp[0];
        const f32x4 v1 = *(const f32x4*)&hp[4];
        #pragma unroll
        for (int u = 0; u < 4; ++u) s_m[(og*8+u)*32 + n] = v0[u];
        #pragma unroll
        for (int u = 0; u < 4; ++u) s_m[(og*8+4+u)*32 + n] = v1[u];
    }
    // CSR gather: agg (rows 67..130) + num/cnt -> coord_out
    {
        const int o0 = off[gn], o1 = off[gn + 1];
        float acc[8];
        #pragma unroll
        for (int u = 0; u < 8; ++u) acc[u] = 0.0f;
        float nx = 0.0f, ny = 0.0f, nz = 0.0f;
        for (int j = o0; j < o1; ++j) {
            const int e2 = eidx[j];
            const float* ep = &ef[(size_t)e2*64 + og*8];
            #pragma unroll
            for (int u = 0; u < 8; ++u) acc[u] += ep[u];
            if (og == 0) {
                nx += trans[e2*3 + 0];
                ny += trans[e2*3 + 1];
                nz += trans[e2*3 + 2];
            }
        }
        #pragma unroll
        for (int u = 0; u < 8; ++u) s_m[(67+og*8+u)*32 + n] = acc[u];
        if (og == 0) {
            const float cnt = fmaxf((float)(o1 - o0), 1.0f);
            out[NN*67 + gn*3 + 0] = coord[gn*3 + 0] + nx / cnt;
            out[NN*67 + gn*3 + 1] = coord[gn*3 + 1] + ny / cnt;
            out[NN*67 + gn*3 + 2] = coord[gn*3 + 2] + nz / cnt;
        }
    }
    // rel for node n comes from edge n (E == N quirk)
    if (t < 32) {
        const int nn2 = n0 + t;
        const int r = ei[nn2], c = ei[EE + nn2];
        const float dx = coord[r*3+0] - coord[c*3+0];
        const float dy = coord[r*3+1] - coord[c*3+1];
        const float dz = coord[r*3+2] - coord[c*3+2];
        const float inv = 1.0f / (sqrtf(dx*dx + dy*dy + dz*dz) + 1e-8f);
        s_m[64*32 + t] = dx*inv;
        s_m[65*32 + t] = dy*inv;
        s_m[66*32 + t] = dz*inv;
    }
    __syncthreads();

    // z = silu(m @ Wn1 + bn1)   (Wn1 from LDS)
    {
        float acc[8];
        #pragma unroll
        for (int u = 0; u < 8; ++u) acc[u] = bn1[og*8 + u];
        for (int q = 0; q < 131; ++q) {
            const float x = s_m[q*32 + n];
            const f32x4 w0 = *(const f32x4*)&s_w[q*64 + og*8];
            const f32x4 w1 = *(const f32x4*)&s_w[q*64 + og*8 + 4];
            #pragma unroll
            for (int u = 0; u < 4; ++u) acc[u]   = fmaf(x, w0[u], acc[u]);
            #pragma unroll
            for (int u = 0; u < 4; ++u) acc[4+u] = fmaf(x, w1[u], acc[4+u]);
        }
        #pragma unroll
        for (int u = 0; u < 8; ++u) s_z[(og*8+u)*32 + n] = siluf(acc[u]);
    }
    __syncthreads();

    for (int i = t*4; i < 64*67; i += 1024)   // 4288 floats; t*4<4288 only
        *(f32x4*)&s_w[i] = *(const f32x4*)&Wn2[i];
    __syncthreads();

    // h_out = h_pos + z @ Wn2 + bn2   (h_pos == m[0:67])
    {
        for (int o = og; o < 67; o += 8) {
            float a = s_m[o*32 + n] + bn2[o];
            for (int k = 0; k < 64; ++k)
                a = fmaf(s_z[k*32 + n], s_w[k*67 + o], a);
            out[(size_t)gn*67 + o] = a;
        }
    }
}

extern "C" void kernel_launch(void* const* d_in, const int* in_sizes, int n_in,
                              void* d_out, int out_size, void* d_ws, size_t ws_size,
                              hipStream_t stream)
{
    (void)in_sizes; (void)n_in; (void)out_size;
    const float* h     = (const float*)d_in[0];
    const float* coord = (const float*)d_in[1];
    const int*   ei    = (const int*)d_in[2];
    const float* We1   = (const float*)d_in[3];
    const float* be1   = (const float*)d_in[4];
    const float* We2   = (const float*)d_in[5];
    const float* be2   = (const float*)d_in[6];
    const float* Ws1   = (const float*)d_in[7];
    const float* bs1   = (const float*)d_in[8];
    const float* Ws2   = (const float*)d_in[9];
    const float* bs2   = (const float*)d_in[10];
    const float* Wc1   = (const float*)d_in[11];
    const float* bc1   = (const float*)d_in[12];
    const float* Wc2   = (const float*)d_in[13];
    const float* Wn1   = (const float*)d_in[14];
    const float* bn1   = (const float*)d_in[15];
    const float* Wn2   = (const float*)d_in[16];
    const float* bn2   = (const float*)d_in[17];
    float* ws  = (float*)d_ws;
    float* out = (float*)d_out;

    float* ef    = ws + WS_EF;
    float* trans = ws + WS_TRANS;
    int* cnti = (int*)(ws + WS_CNTI);
    int* off  = (int*)(ws + WS_OFF);
    int* cur  = (int*)(ws + WS_CUR);
    int* eidx = (int*)(ws + WS_EIDX);

    const size_t need_all = (size_t)WS_CORE_END * sizeof(float) + (size_t)WS1S_ELEMS * 2;
    unsigned short* ws1s = (ws_size >= need_all) ? (unsigned short*)(ws + WS_CORE_END)
                                                 : (unsigned short*)d_out;  // node kernel rewrites d_out afterwards

    hipMemsetAsync((void*)cnti, 0, (size_t)NN * sizeof(int), stream);
    hist_csr<<<(EE + 255)/256, 256, 0, stream>>>(ei, cnti);
    scan_csr<<<1, 1024, 0, stream>>>(cnti, off, cur);
    fill_csr<<<(EE + 255)/256, 256, 0, stream>>>(ei, cur, eidx);
    swz_ws1<<<256, 256, 0, stream>>>(Ws1, ws1s);
    egcl_edge_kernel<<<EE/32, 512, 0, stream>>>(h, coord, ei, We1, be1, We2, be2,
                                                ws1s, bs1, Ws2, bs2, Wc1, bc1, Wc2,
                                                ef, trans);
    egcl_node_kernel<<<NN/32, 256, 0, stream>>>(h, coord, ei, Wn1, bn1, Wn2, bn2,
                                                ef, trans, off, eidx, out);
}

// Round 10
// 116.887 us; speedup vs baseline: 3.1043x; 1.2691x over previous
//
#include <hip/hip_runtime.h>

#define NN 20000
#define EE 20000

typedef __attribute__((ext_vector_type(8))) short short8;
typedef __attribute__((ext_vector_type(4))) float f32x4;

// workspace layout (float indices)
#define WS_EF     0                         // edge_feat [E][64]
#define WS_TRANS  (WS_EF + EE*64)           // trans [E][3]
#define WS_CNTI   (WS_TRANS + EE*3)         // int cnt[N]
#define WS_OFF    (WS_CNTI + NN)            // int off[N+1]
#define WS_CUR    (WS_OFF + NN + 1)         // int cursor[N]
#define WS_EIDX   (WS_CUR + NN)             // int eidx[E]
#define WS_CORE_END (WS_EIDX + EE)
#define WS_AL     ((WS_CORE_END + 3) & ~3)  // 16B-align the bf16 scratch
#define WS1S_ELEMS (4096*128)               // bf16: swizzled 64*Ws1 (1 MB)
#define FB_ELEMS   26624                    // bf16: MLP weight frag buffers
// fb sub-offsets (bf16 elems)
#define FB_WE1 0        // K=129->160, 5 steps : 10240
#define FB_WE2 10240    // K=64, 2 steps       : 4096
#define FB_WS2 14336    // K=128, 4 steps      : 8192
#define FB_WC1 22528    // K=64, 2 steps       : 4096

// edge-kernel LDS (f32 indices)
#define AIN_F   0        // A_in bf16 [32][336B] = 2688 f32 ; later T1A bf16 [32][272B]
#define WBA_F   2688     // frag buf A: We1(5120) / Ws2(4096)
#define WBB_F   7808     // frag buf B: We2(2048) / Wc1(2048)
#define E1A_F   9856     // e1 / ef bf16 A-form [32][144B] = 1152
#define GF32_F  11008    // g f32 [64][36] = 2304 ; later v f32
#define GA_F    13312    // g bf16 A-form [32][144B] = 1152
#define SM_FLOATS 14464  // 57.9 KB
// byte offsets
#define AIN_B   0
#define T1A_B   0
#define WBA_B   (WBA_F*4)
#define WBB_B   (WBB_F*4)
#define E1A_B   (E1A_F*4)
#define EFA_B   (E1A_F*4)
#define GA_B    (GA_F*4)

__device__ __forceinline__ float siluf(float x) {
    return x * (1.0f / (1.0f + __expf(-x)));
}
__device__ __forceinline__ unsigned short f2bf(float f) {
    union { float f; unsigned u; } v; v.f = f;
    return (unsigned short)((v.u + 0x7FFF + ((v.u >> 16) & 1)) >> 16);
}

// ---------- CSR build ----------
__global__ void scan_csr(const int* __restrict__ cnt, int* __restrict__ off,
                         int* __restrict__ cursor) {
    const int t = threadIdx.x;        // 1024 threads, 20 items each
    __shared__ int ps[1024];
    int loc[20];
    int s = 0;
    const int base = t * 20;
    #pragma unroll
    for (int k = 0; k < 20; ++k) {
        const int i = base + k;
        const int c = (i < NN) ? cnt[i] : 0;
        loc[k] = s; s += c;
    }
    ps[t] = s;
    __syncthreads();
    for (int d = 1; d < 1024; d <<= 1) {
        const int v = (t >= d) ? ps[t - d] : 0;
        __syncthreads();
        ps[t] += v;
        __syncthreads();
    }
    const int excl = ps[t] - s;
    #pragma unroll
    for (int k = 0; k < 20; ++k) {
        const int i = base + k;
        if (i < NN) { const int v = excl + loc[k]; off[i] = v; cursor[i] = v; }
    }
    if (t == 1023) off[NN] = ps[1023];
}

__global__ void fill_csr(const int* __restrict__ ei, int* __restrict__ cursor,
                         int* __restrict__ eidx) {
    const int e = blockIdx.x * 256 + threadIdx.x;
    if (e < EE) {
        const int p = atomicAdd(&cursor[ei[e]], 1);
        eidx[p] = e;
    }
}

// ---------- combined prep: SO3 B swizzle + MLP frag buffers + degree histogram ----------
__global__ void prep_all(const float* __restrict__ Ws1,
                         const float* __restrict__ We1, const float* __restrict__ We2,
                         const float* __restrict__ Ws2, const float* __restrict__ Wc1,
                         unsigned short* __restrict__ ws1s, unsigned short* __restrict__ fbb,
                         const int* __restrict__ ei, int* __restrict__ cnt)
{
    const int b = blockIdx.x, t = threadIdx.x;
    if (b < 256) {
        // ws1s[((s*8+tn)*64 + l)*8 + u] = bf16(64*Ws1[(s*32 + 8*(l>>4) + u)][tn*16 + (l&15)])
        const int tid = b * 256 + t;
        const int l = tid & 63, fid = tid >> 6;
        const int s = fid >> 3, tn = fid & 7;
        const int krow = s * 32 + 8 * (l >> 4);
        const int ncol = tn * 16 + (l & 15);
        short8 frag;
        #pragma unroll
        for (int u = 0; u < 8; ++u)
            frag[u] = (short)f2bf(64.0f * Ws1[(krow + u) * 128 + ncol]);
        *(short8*)&ws1s[(size_t)tid * 8] = frag;
    } else if (b < 269) {
        // MLP weight frags: dst[local*8+u] = bf16(W[s*32+8*(l>>4)+u][tn*16+(l&15)]), 0 past K
        const int idx = (b - 256) * 256 + t;   // 0..3327
        const float* W; int K; unsigned short* dst; int local;
        if (idx < 1280)      { W = We1; K = 129; dst = fbb + FB_WE1; local = idx; }
        else if (idx < 1792) { W = We2; K = 64;  dst = fbb + FB_WE2; local = idx - 1280; }
        else if (idx < 2816) { W = Ws2; K = 128; dst = fbb + FB_WS2; local = idx - 1792; }
        else                 { W = Wc1; K = 64;  dst = fbb + FB_WC1; local = idx - 2816; }
        const int s = local >> 8, rem = local & 255, tn = rem >> 6, ll = rem & 63;
        const int ccol = tn * 16 + (ll & 15), kr0 = s * 32 + 8 * (ll >> 4);
        short8 frag;
        #pragma unroll
        for (int u = 0; u < 8; ++u) {
            const int kr = kr0 + u;
            frag[u] = (kr < K) ? (short)f2bf(W[kr * 64 + ccol]) : (short)0;
        }
        *(short8*)&dst[local * 8] = frag;
    } else {
        const int e = (b - 269) * 256 + t;
        if (e < EE) atomicAdd(&cnt[ei[e]], 1);
    }
}

// __launch_bounds__(512, 2): arg2 = min waves/EU; 512-thr block = 2 waves/EU
// => VGPR cap 128 (the SO3 register banks need ~112; "4" would cap 64 and spill).
__global__ __launch_bounds__(512, 2)
void egcl_edge_kernel(const float* __restrict__ h, const float* __restrict__ coord,
                      const int* __restrict__ ei,
                      const unsigned short* __restrict__ fb,
                      const float* __restrict__ be1, const float* __restrict__ be2,
                      const unsigned short* __restrict__ Ws1s, const float* __restrict__ bs1,
                      const float* __restrict__ bs2, const float* __restrict__ bc1,
                      const float* __restrict__ Wc2,
                      float* __restrict__ ef_out, float* __restrict__ trans_out)
{
    __shared__ __attribute__((aligned(16))) float sm[SM_FLOATS];
    __shared__ int s_row[32], s_col[32];
    __shared__ float s_cd[96], s_rad[32];

    const int t = threadIdx.x;
    const int e0 = blockIdx.x * 32;    // 625 * 32 == 20000
    const int l = t & 63, w = t >> 6;
    const int mt = w & 1, tn4 = w >> 1;     // MLP wave tile: rows [mt*16,+16), cols [tn4*16,+16)
    const int kg = l >> 4;
    const int arow = mt * 16 + (l & 15);    // A-operand row this lane reads
    const int akoff = kg * 16;              // A-operand k-chunk byte offset
    const int orow = mt * 16 + (kg << 2);   // C/D row base this lane owns
    const int col = tn4 * 16 + (l & 15);    // C/D col this lane owns

#define STAGEFB(DSTF, SRC, NBF16) { \
    const unsigned short* _s = (SRC); \
    for (int i = t*8; i < (NBF16); i += 4096) \
        *(f32x4*)&sm[(DSTF) + (i >> 1)] = *(const f32x4*)&_s[i]; }

    if (t < 32) {
        const int r = ei[e0 + t], c = ei[EE + e0 + t];
        s_row[t] = r; s_col[t] = c;
        const float dx = coord[r*3+0] - coord[c*3+0];
        const float dy = coord[r*3+1] - coord[c*3+1];
        const float dz = coord[r*3+2] - coord[c*3+2];
        s_cd[t] = dx; s_cd[32+t] = dy; s_cd[64+t] = dz;
        s_rad[t] = dx*dx + dy*dy + dz*dz;
    }
    __syncthreads();

    // P1: gather A_in bf16 [32 e][160 k pad168] = [h_row(64), h_col(64), radial, zeros]
    //     + stage We1/We2 frag buffers
    {
        const int ee = t >> 4, fg = t & 15;
        const int r = s_row[ee], c = s_col[ee];
        const float* src = (fg < 8) ? &h[(size_t)r*64 + fg*8] : &h[(size_t)c*64 + (fg-8)*8];
        short8 frag;
        #pragma unroll
        for (int u = 0; u < 8; ++u) frag[u] = (short)f2bf(src[u]);
        *(short8*)((char*)sm + AIN_B + ee*336 + fg*16) = frag;
        if (fg < 5) {   // chunks 16..20: cols 128..167 (radial + zero pad; kills stale NaNs)
            short8 z = {0,0,0,0,0,0,0,0};
            if (fg == 0) z[0] = (short)f2bf(s_rad[ee]);
            *(short8*)((char*)sm + AIN_B + ee*336 + (16 + fg)*16) = z;
        }
    }
    STAGEFB(WBA_F, fb + FB_WE1, 10240)
    STAGEFB(WBB_F, fb + FB_WE2, 4096)
    __syncthreads();

    // P2: e1 = silu(in @ We1 + be1)  (MFMA, K=160 zero-padded) -> E1A bf16
    {
        f32x4 acc = {0.f, 0.f, 0.f, 0.f};
        #pragma unroll
        for (int s = 0; s < 5; ++s) {
            const short8 a = *(const short8*)((const char*)sm + AIN_B + arow*336 + s*64 + akoff);
            const short8 b = *(const short8*)((const char*)sm + WBA_B + ((s*4 + tn4)*64 + l)*16);
            acc = __builtin_amdgcn_mfma_f32_16x16x32_bf16(a, b, acc, 0, 0, 0);
        }
        const float bb = be1[col];
        #pragma unroll
        for (int r = 0; r < 4; ++r)
            *(unsigned short*)((char*)sm + E1A_B + (orow + r)*144 + col*2)
                = f2bf(siluf(acc[r] + bb));
    }
    __syncthreads();

    // P3: g = silu(e1 @ We2 + be2) (MFMA) -> GF32 (f32, merge factor) + GA (bf16 A-form)
    //     + stage Ws2 frags (WB_A free after P2)
    {
        f32x4 acc = {0.f, 0.f, 0.f, 0.f};
        #pragma unroll
        for (int s = 0; s < 2; ++s) {
            const short8 a = *(const short8*)((const char*)sm + E1A_B + arow*144 + s*64 + akoff);
            const short8 b = *(const short8*)((const char*)sm + WBB_B + ((s*4 + tn4)*64 + l)*16);
            acc = __builtin_amdgcn_mfma_f32_16x16x32_bf16(a, b, acc, 0, 0, 0);
        }
        const float bb = be2[col];
        #pragma unroll
        for (int r = 0; r < 4; ++r) {
            const float sv = siluf(acc[r] + bb);
            sm[GF32_F + col*36 + orow + r] = sv;
            *(unsigned short*)((char*)sm + GA_B + (orow + r)*144 + col*2) = f2bf(sv);
        }
    }
    STAGEFB(WBA_F, fb + FB_WS2, 8192)
    __syncthreads();

    // P4: SO3 GEMM acc[e,k] = sum_i g[e,i]*(g_bf16[e,:] @ 64*Ws1_i[:,k])
    // (R8-proven: B L2->registers, two 8-step banks, compiler-counted vmcnt, no barriers)
    short8 A[2][2];
    #pragma unroll
    for (int et = 0; et < 2; ++et)
        #pragma unroll
        for (int kh = 0; kh < 2; ++kh)
            A[et][kh] = *(const short8*)((const char*)sm + GA_B +
                                         (et*16 + (l & 15))*144 + kh*64 + kg*16);

    float accv[2][4];
    #pragma unroll
    for (int et = 0; et < 2; ++et)
        #pragma unroll
        for (int r = 0; r < 4; ++r) accv[et][r] = 0.0f;

    {
        const short8* Bp = (const short8*)Ws1s;   // frag for step s: Bp[(s*8 + w)*64 + l]
        short8 pA[8], pB[8];

#define LOADBANK(P, BASE) { \
    _Pragma("unroll") \
    for (int j = 0; j < 8; ++j) P[j] = Bp[(((BASE)+j)*8 + w)*64 + l]; \
    __builtin_amdgcn_sched_barrier(0); }
#define USEBANK(P, BASE) { \
    _Pragma("unroll") \
    for (int k = 0; k < 4; ++k) { \
        f32x4 c0 = __builtin_amdgcn_mfma_f32_16x16x32_bf16(A[0][0], P[2*k],   (f32x4){0.f,0.f,0.f,0.f}, 0, 0, 0); \
        f32x4 c1 = __builtin_amdgcn_mfma_f32_16x16x32_bf16(A[1][0], P[2*k],   (f32x4){0.f,0.f,0.f,0.f}, 0, 0, 0); \
        c0 = __builtin_amdgcn_mfma_f32_16x16x32_bf16(A[0][1], P[2*k+1], c0, 0, 0, 0); \
        c1 = __builtin_amdgcn_mfma_f32_16x16x32_bf16(A[1][1], P[2*k+1], c1, 0, 0, 0); \
        const int i_ = (BASE)/2 + k; \
        const f32x4 g0 = *(const f32x4*)&sm[GF32_F + i_*36 + (kg << 2)]; \
        const f32x4 g1 = *(const f32x4*)&sm[GF32_F + i_*36 + 16 + (kg << 2)]; \
        _Pragma("unroll") \
        for (int r = 0; r < 4; ++r) { \
            accv[0][r] = fmaf(g0[r], c0[r], accv[0][r]); \
            accv[1][r] = fmaf(g1[r], c1[r], accv[1][r]); \
        } \
    } }

        LOADBANK(pA, 0)
        LOADBANK(pB, 8)
        #pragma unroll 1
        for (int m = 0; m < 7; ++m) {
            USEBANK(pA, 16*m)
            LOADBANK(pA, 16*m + 16)
            USEBANK(pB, 16*m + 8)
            LOADBANK(pB, 16*m + 24)
        }
        USEBANK(pA, 112)
        USEBANK(pB, 120)
#undef LOADBANK
#undef USEBANK
    }

    // t1 = relu(acc + bs1) -> T1A bf16 A-form [32 e][128 k] (over dead A_in region)
    {
        const int kcol = w*16 + (l & 15);
        const float bk = bs1[kcol];
        #pragma unroll
        for (int et = 0; et < 2; ++et)
            #pragma unroll
            for (int r = 0; r < 4; ++r)
                *(unsigned short*)((char*)sm + T1A_B + (et*16 + (kg<<2) + r)*272 + kcol*2)
                    = f2bf(fmaxf(accv[et][r] + bk, 0.0f));
    }
    STAGEFB(WBB_F, fb + FB_WC1, 4096)   // WB_B free after P3
    __syncthreads();

    // P5: ef = t1 @ Ws2 + bs2 (MFMA, K=128) -> global ef_out + EFA bf16 (over E1A)
    {
        f32x4 acc = {0.f, 0.f, 0.f, 0.f};
        #pragma unroll
        for (int s = 0; s < 4; ++s) {
            const short8 a = *(const short8*)((const char*)sm + T1A_B + arow*272 + s*64 + akoff);
            const short8 b = *(const short8*)((const char*)sm + WBA_B + ((s*4 + tn4)*64 + l)*16);
            acc = __builtin_amdgcn_mfma_f32_16x16x32_bf16(a, b, acc, 0, 0, 0);
        }
        const float bb = bs2[col];
        #pragma unroll
        for (int r = 0; r < 4; ++r) {
            const float ev = acc[r] + bb;
            ef_out[(size_t)(e0 + orow + r)*64 + col] = ev;
            *(unsigned short*)((char*)sm + EFA_B + (orow + r)*144 + col*2) = f2bf(ev);
        }
    }
    __syncthreads();

    // P6: v = silu(ef @ Wc1 + bc1) (MFMA) -> V f32 (over dead GF32)
    {
        f32x4 acc = {0.f, 0.f, 0.f, 0.f};
        #pragma unroll
        for (int s = 0; s < 2; ++s) {
            const short8 a = *(const short8*)((const char*)sm + EFA_B + arow*144 + s*64 + akoff);
            const short8 b = *(const short8*)((const char*)sm + WBB_B + ((s*4 + tn4)*64 + l)*16);
            acc = __builtin_amdgcn_mfma_f32_16x16x32_bf16(a, b, acc, 0, 0, 0);
        }
        const float bb = bc1[col];
        #pragma unroll
        for (int r = 0; r < 4; ++r)
            sm[GF32_F + col*36 + orow + r] = siluf(acc[r] + bb);
    }
    __syncthreads();

    // P7: cw = v . Wc2 -> trans
    if (t < 32) {
        float cw = 0.0f;
        for (int f = 0; f < 64; ++f) cw = fmaf(sm[GF32_F + f*36 + t], Wc2[f], cw);
        const int eid = e0 + t;
        trans_out[eid*3 + 0] = s_cd[t]    * cw;
        trans_out[eid*3 + 1] = s_cd[32+t] * cw;
        trans_out[eid*3 + 2] = s_cd[64+t] * cw;
    }
#undef STAGEFB
}

__global__ __launch_bounds__(256, 2)
void egcl_node_kernel(const float* __restrict__ h, const float* __restrict__ coord,
                      const int* __restrict__ ei,
                      const float* __restrict__ Wn1, const float* __restrict__ bn1,
                      const float* __restrict__ Wn2, const float* __restrict__ bn2,
                      const float* __restrict__ ef, const float* __restrict__ trans,
                      const int* __restrict__ off, const int* __restrict__ eidx,
                      float* __restrict__ out)
{
    __shared__ float s_m[131*32];
    __shared__ float s_z[64*32];
    __shared__ float s_w[131*64];   // Wn1 staged, then Wn2
    const int t = threadIdx.x;
    const int n0 = blockIdx.x * 32;
    const int n = t >> 3, og = t & 7;
    const int gn = n0 + n;

    for (int i = t*4; i < 131*64; i += 1024)
        *(f32x4*)&s_w[i] = *(const f32x4*)&Wn1[i];

    {
        const float* hp = &h[(size_t)gn*64 + og*8];
        const f32x4 v0 = *(const f32x4*)&hp[0];
        const f32x4 v1 = *(const f32x4*)&hp[4];
        #pragma unroll
        for (int u = 0; u < 4; ++u) s_m[(og*8+u)*32 + n] = v0[u];
        #pragma unroll
        for (int u = 0; u < 4; ++u) s_m[(og*8+4+u)*32 + n] = v1[u];
    }
    {
        const int o0 = off[gn], o1 = off[gn + 1];
        float acc[8];
        #pragma unroll
        for (int u = 0; u < 8; ++u) acc[u] = 0.0f;
        float nx = 0.0f, ny = 0.0f, nz = 0.0f;
        for (int j = o0; j < o1; ++j) {
            const int e2 = eidx[j];
            const float* ep = &ef[(size_t)e2*64 + og*8];
            #pragma unroll
            for (int u = 0; u < 8; ++u) acc[u] += ep[u];
            if (og == 0) {
                nx += trans[e2*3 + 0];
                ny += trans[e2*3 + 1];
                nz += trans[e2*3 + 2];
            }
        }
        #pragma unroll
        for (int u = 0; u < 8; ++u) s_m[(67+og*8+u)*32 + n] = acc[u];
        if (og == 0) {
            const float cnt = fmaxf((float)(o1 - o0), 1.0f);
            out[NN*67 + gn*3 + 0] = coord[gn*3 + 0] + nx / cnt;
            out[NN*67 + gn*3 + 1] = coord[gn*3 + 1] + ny / cnt;
            out[NN*67 + gn*3 + 2] = coord[gn*3 + 2] + nz / cnt;
        }
    }
    if (t < 32) {   // rel for node n comes from edge n (E == N quirk)
        const int nn2 = n0 + t;
        const int r = ei[nn2], c = ei[EE + nn2];
        const float dx = coord[r*3+0] - coord[c*3+0];
        const float dy = coord[r*3+1] - coord[c*3+1];
        const float dz = coord[r*3+2] - coord[c*3+2];
        const float inv = 1.0f / (sqrtf(dx*dx + dy*dy + dz*dz) + 1e-8f);
        s_m[64*32 + t] = dx*inv;
        s_m[65*32 + t] = dy*inv;
        s_m[66*32 + t] = dz*inv;
    }
    __syncthreads();

    {
        float acc[8];
        #pragma unroll
        for (int u = 0; u < 8; ++u) acc[u] = bn1[og*8 + u];
        for (int q = 0; q < 131; ++q) {
            const float x = s_m[q*32 + n];
            const f32x4 w0 = *(const f32x4*)&s_w[q*64 + og*8];
            const f32x4 w1 = *(const f32x4*)&s_w[q*64 + og*8 + 4];
            #pragma unroll
            for (int u = 0; u < 4; ++u) acc[u]   = fmaf(x, w0[u], acc[u]);
            #pragma unroll
            for (int u = 0; u < 4; ++u) acc[4+u] = fmaf(x, w1[u], acc[4+u]);
        }
        #pragma unroll
        for (int u = 0; u < 8; ++u) s_z[(og*8+u)*32 + n] = siluf(acc[u]);
    }
    __syncthreads();

    for (int i = t*4; i < 64*67; i += 1024)
        *(f32x4*)&s_w[i] = *(const f32x4*)&Wn2[i];
    __syncthreads();

    {
        for (int o = og; o < 67; o += 8) {
            float a = s_m[o*32 + n] + bn2[o];
            for (int k = 0; k < 64; ++k)
                a = fmaf(s_z[k*32 + n], s_w[k*67 + o], a);
            out[(size_t)gn*67 + o] = a;
        }
    }
}

extern "C" void kernel_launch(void* const* d_in, const int* in_sizes, int n_in,
                              void* d_out, int out_size, void* d_ws, size_t ws_size,
                              hipStream_t stream)
{
    (void)in_sizes; (void)n_in; (void)out_size;
    const float* h     = (const float*)d_in[0];
    const float* coord = (const float*)d_in[1];
    const int*   ei    = (const int*)d_in[2];
    const float* We1   = (const float*)d_in[3];
    const float* be1   = (const float*)d_in[4];
    const float* We2   = (const float*)d_in[5];
    const float* be2   = (const float*)d_in[6];
    const float* Ws1   = (const float*)d_in[7];
    const float* bs1   = (const float*)d_in[8];
    const float* Ws2   = (const float*)d_in[9];
    const float* bs2   = (const float*)d_in[10];
    const float* Wc1   = (const float*)d_in[11];
    const float* bc1   = (const float*)d_in[12];
    const float* Wc2   = (const float*)d_in[13];
    const float* Wn1   = (const float*)d_in[14];
    const float* bn1   = (const float*)d_in[15];
    const float* Wn2   = (const float*)d_in[16];
    const float* bn2   = (const float*)d_in[17];
    float* ws  = (float*)d_ws;
    float* out = (float*)d_out;

    float* ef    = ws + WS_EF;
    float* trans = ws + WS_TRANS;
    int* cnti = (int*)(ws + WS_CNTI);
    int* off  = (int*)(ws + WS_OFF);
    int* cur  = (int*)(ws + WS_CUR);
    int* eidx = (int*)(ws + WS_EIDX);

    const size_t need_all = (size_t)WS_AL * 4 + (size_t)(WS1S_ELEMS + FB_ELEMS) * 2;
    unsigned short* ws1s = (ws_size >= need_all) ? (unsigned short*)(ws + WS_AL)
                                                 : (unsigned short*)d_out;  // node kernel rewrites d_out afterwards
    unsigned short* fbb = ws1s + WS1S_ELEMS;

    hipMemsetAsync((void*)cnti, 0, (size_t)NN * sizeof(int), stream);
    prep_all<<<348, 256, 0, stream>>>(Ws1, We1, We2, Ws2, Wc1, ws1s, fbb, ei, cnti);
    scan_csr<<<1, 1024, 0, stream>>>(cnti, off, cur);
    fill_csr<<<(EE + 255)/256, 256, 0, stream>>>(ei, cur, eidx);
    egcl_edge_kernel<<<EE/32, 512, 0, stream>>>(h, coord, ei, fbb, be1, be2,
                                                ws1s, bs1, bs2, bc1, Wc2,
                                                ef, trans);
    egcl_node_kernel<<<NN/32, 256, 0, stream>>>(h, coord, ei, Wn1, bn1, Wn2, bn2,
                                                ef, trans, off, eidx, out);
}

// Round 11
// 100.309 us; speedup vs baseline: 3.6174x; 1.1653x over previous
//
#include <hip/hip_runtime.h>

#define NN 20000
#define EE 20000

typedef __attribute__((ext_vector_type(8))) short short8;
typedef __attribute__((ext_vector_type(4))) float f32x4;

// workspace layout (float indices)
#define WS_EFB    0                         // edge_feat bf16 [E][64] = 640000 f32 units
#define WS_TRANS  640000                    // trans f32 [E][3]
#define WS_CNTI   700000                    // int cnt[N]
#define WS_OFF    720000                    // int off[N+1]
#define WS_CUR    740001                    // int cursor[N]
#define WS_EIDX   760001                    // int eidx[E]
#define WS_CORE_END 780001
#define WS_AL     ((WS_CORE_END + 3) & ~3)
#define WS1S_ELEMS (4096*128)               // bf16: swizzled 64*Ws1 (1 MB)
// MLP weight fragment buffers (bf16 elems)
#define FB_WE1 0        // K=129->160, 5 steps : 10240
#define FB_WE2 10240    // K=64, 2 steps       : 4096
#define FB_WS2 14336    // K=128, 4 steps      : 8192
#define FB_WC1 22528    // K=64, 2 steps       : 4096
#define FB_WN1 26624    // K=131->160, 5 steps : 10240
#define FB_WN2 36864    // K=64, 2 steps, 5 tn : 5120
#define FB_ELEMS 41984
// total ws need: 780004*4 + (524288+41984)*2 = 4,252,560 B  (< 5.68 MB proven avail)

// edge-kernel LDS (f32 indices)
#define AIN_F   0        // A_in bf16 [32][336B] ; later T1A bf16 [32][272B]
#define WBA_F   2688     // frag buf A: We1(5120 f32) / Ws2(4096)
#define WBB_F   7808     // frag buf B: We2(2048) / Wc1(2048)
#define E1A_F   9856     // e1 / ef bf16 A-form [32][144B]
#define GF32_F  11008    // g f32 [64][36] ; later v f32
#define GA_F    13312    // g bf16 A-form [32][144B]
#define SM_FLOATS 14464
#define AIN_B   0
#define T1A_B   0
#define WBA_B   (WBA_F*4)
#define WBB_B   (WBB_F*4)
#define E1A_B   (E1A_F*4)
#define EFA_B   (E1A_F*4)
#define GA_B    (GA_F*4)

// node-kernel LDS (f32 indices)
#define NMA_B   0        // m bf16 [32][336B] = 2688 f32
#define NHP_F   2688     // h_pos f32 [32][68] = 2176
#define NW1_F   4864     // Wn1 frags 10240 bf16 = 5120 f32
#define NW2_F   9984     // Wn2 frags 5120 bf16 = 2560 f32
#define NZA_F   12544    // z bf16 A-form [32][144B] = 1152 f32
#define NSM_FLOATS 13696 // 54.8 KB
#define NW1_B   (NW1_F*4)
#define NW2_B   (NW2_F*4)
#define NZA_B   (NZA_F*4)

__device__ __forceinline__ float siluf(float x) {
    return x * (1.0f / (1.0f + __expf(-x)));
}
__device__ __forceinline__ unsigned short f2bf(float f) {
    union { float f; unsigned u; } v; v.f = f;
    return (unsigned short)((v.u + 0x7FFF + ((v.u >> 16) & 1)) >> 16);
}
__device__ __forceinline__ float bf2f(unsigned short x) {
    union { unsigned u; float f; } v; v.u = ((unsigned)x) << 16; return v.f;
}

// ---------- CSR build ----------
__global__ void scan_csr(const int* __restrict__ cnt, int* __restrict__ off,
                         int* __restrict__ cursor) {
    const int t = threadIdx.x;        // 1024 threads, 20 items each
    __shared__ int ps[1024];
    int loc[20];
    int s = 0;
    const int base = t * 20;
    #pragma unroll
    for (int k = 0; k < 20; ++k) {
        const int i = base + k;
        const int c = (i < NN) ? cnt[i] : 0;
        loc[k] = s; s += c;
    }
    ps[t] = s;
    __syncthreads();
    for (int d = 1; d < 1024; d <<= 1) {
        const int v = (t >= d) ? ps[t - d] : 0;
        __syncthreads();
        ps[t] += v;
        __syncthreads();
    }
    const int excl = ps[t] - s;
    #pragma unroll
    for (int k = 0; k < 20; ++k) {
        const int i = base + k;
        if (i < NN) { const int v = excl + loc[k]; off[i] = v; cursor[i] = v; }
    }
    if (t == 1023) off[NN] = ps[1023];
}

__global__ void fill_csr(const int* __restrict__ ei, int* __restrict__ cursor,
                         int* __restrict__ eidx) {
    const int e = blockIdx.x * 256 + threadIdx.x;
    if (e < EE) {
        const int p = atomicAdd(&cursor[ei[e]], 1);
        eidx[p] = e;
    }
}

// ---------- combined prep: SO3 B swizzle + all MLP frag buffers + degree histogram ----------
__global__ void prep_all(const float* __restrict__ Ws1,
                         const float* __restrict__ We1, const float* __restrict__ We2,
                         const float* __restrict__ Ws2, const float* __restrict__ Wc1,
                         const float* __restrict__ Wn1, const float* __restrict__ Wn2,
                         unsigned short* __restrict__ ws1s, unsigned short* __restrict__ fbb,
                         const int* __restrict__ ei, int* __restrict__ cnt)
{
    const int b = blockIdx.x, t = threadIdx.x;
    if (b < 256) {
        // ws1s[((s*8+tn)*64 + l)*8 + u] = bf16(64*Ws1[(s*32 + 8*(l>>4) + u)][tn*16 + (l&15)])
        const int tid = b * 256 + t;
        const int l = tid & 63, fid = tid >> 6;
        const int s = fid >> 3, tn = fid & 7;
        const int krow = s * 32 + 8 * (l >> 4);
        const int ncol = tn * 16 + (l & 15);
        short8 frag;
        #pragma unroll
        for (int u = 0; u < 8; ++u)
            frag[u] = (short)f2bf(64.0f * Ws1[(krow + u) * 128 + ncol]);
        *(short8*)&ws1s[(size_t)tid * 8] = frag;
    } else if (b < 277) {
        const int idx = (b - 256) * 256 + t;   // 0..5375, valid < 5248
        if (idx < 5248) {
            const float* W; int K, NC, NTN; unsigned short* dst; int local;
            if (idx < 1280)      { W = We1; K = 129; NC = 64; NTN = 4; dst = fbb + FB_WE1; local = idx; }
            else if (idx < 1792) { W = We2; K = 64;  NC = 64; NTN = 4; dst = fbb + FB_WE2; local = idx - 1280; }
            else if (idx < 2816) { W = Ws2; K = 128; NC = 64; NTN = 4; dst = fbb + FB_WS2; local = idx - 1792; }
            else if (idx < 3328) { W = Wc1; K = 64;  NC = 64; NTN = 4; dst = fbb + FB_WC1; local = idx - 2816; }
            else if (idx < 4608) { W = Wn1; K = 131; NC = 64; NTN = 4; dst = fbb + FB_WN1; local = idx - 3328; }
            else                 { W = Wn2; K = 64;  NC = 67; NTN = 5; dst = fbb + FB_WN2; local = idx - 4608; }
            const int per = NTN * 64;
            const int s = local / per, rem = local % per, tn = rem >> 6, ll = rem & 63;
            const int ccol = tn * 16 + (ll & 15), kr0 = s * 32 + 8 * (ll >> 4);
            short8 frag;
            #pragma unroll
            for (int u = 0; u < 8; ++u) {
                const int kr = kr0 + u;
                frag[u] = (kr < K && ccol < NC) ? (short)f2bf(W[kr * NC + ccol]) : (short)0;
            }
            *(short8*)&dst[local * 8] = frag;
        }
    } else {
        const int e = (b - 277) * 256 + t;
        if (e < EE) atomicAdd(&cnt[ei[e]], 1);
    }
}

// __launch_bounds__(512, 2): arg2 = min waves/EU; 512-thr block = 2 waves/EU
// => VGPR cap 128 (the SO3 register banks need ~112; "4" would cap 64 and spill).
__global__ __launch_bounds__(512, 2)
void egcl_edge_kernel(const float* __restrict__ h, const float* __restrict__ coord,
                      const int* __restrict__ ei,
                      const unsigned short* __restrict__ fb,
                      const float* __restrict__ be1, const float* __restrict__ be2,
                      const unsigned short* __restrict__ Ws1s, const float* __restrict__ bs1,
                      const float* __restrict__ bs2, const float* __restrict__ bc1,
                      const float* __restrict__ Wc2,
                      unsigned short* __restrict__ efb_out, float* __restrict__ trans_out)
{
    __shared__ __attribute__((aligned(16))) float sm[SM_FLOATS];
    __shared__ int s_row[32], s_col[32];
    __shared__ float s_cd[96], s_rad[32];

    const int t = threadIdx.x;
    const int e0 = blockIdx.x * 32;    // 625 * 32 == 20000
    const int l = t & 63, w = t >> 6;
    const int mt = w & 1, tn4 = w >> 1;
    const int kg = l >> 4;
    const int arow = mt * 16 + (l & 15);
    const int akoff = kg * 16;
    const int orow = mt * 16 + (kg << 2);
    const int col = tn4 * 16 + (l & 15);

#define STAGEFB(DSTF, SRC, NBF16) { \
    const unsigned short* _s = (SRC); \
    for (int i = t*8; i < (NBF16); i += 4096) \
        *(f32x4*)&sm[(DSTF) + (i >> 1)] = *(const f32x4*)&_s[i]; }

    if (t < 32) {
        const int r = ei[e0 + t], c = ei[EE + e0 + t];
        s_row[t] = r; s_col[t] = c;
        const float dx = coord[r*3+0] - coord[c*3+0];
        const float dy = coord[r*3+1] - coord[c*3+1];
        const float dz = coord[r*3+2] - coord[c*3+2];
        s_cd[t] = dx; s_cd[32+t] = dy; s_cd[64+t] = dz;
        s_rad[t] = dx*dx + dy*dy + dz*dz;
    }
    __syncthreads();

    // P1: gather A_in bf16 [32 e][160k pad] + stage We1/We2 frags
    {
        const int ee = t >> 4, fg = t & 15;
        const int r = s_row[ee], c = s_col[ee];
        const float* src = (fg < 8) ? &h[(size_t)r*64 + fg*8] : &h[(size_t)c*64 + (fg-8)*8];
        short8 frag;
        #pragma unroll
        for (int u = 0; u < 8; ++u) frag[u] = (short)f2bf(src[u]);
        *(short8*)((char*)sm + AIN_B + ee*336 + fg*16) = frag;
        if (fg < 5) {
            short8 z = {0,0,0,0,0,0,0,0};
            if (fg == 0) z[0] = (short)f2bf(s_rad[ee]);
            *(short8*)((char*)sm + AIN_B + ee*336 + (16 + fg)*16) = z;
        }
    }
    STAGEFB(WBA_F, fb + FB_WE1, 10240)
    STAGEFB(WBB_F, fb + FB_WE2, 4096)
    __syncthreads();

    // P2: e1 = silu(in @ We1 + be1) (MFMA, K=160) -> E1A bf16
    {
        f32x4 acc = {0.f, 0.f, 0.f, 0.f};
        #pragma unroll
        for (int s = 0; s < 5; ++s) {
            const short8 a = *(const short8*)((const char*)sm + AIN_B + arow*336 + s*64 + akoff);
            const short8 b = *(const short8*)((const char*)sm + WBA_B + ((s*4 + tn4)*64 + l)*16);
            acc = __builtin_amdgcn_mfma_f32_16x16x32_bf16(a, b, acc, 0, 0, 0);
        }
        const float bb = be1[col];
        #pragma unroll
        for (int r = 0; r < 4; ++r)
            *(unsigned short*)((char*)sm + E1A_B + (orow + r)*144 + col*2)
                = f2bf(siluf(acc[r] + bb));
    }
    __syncthreads();

    // P3: g = silu(e1 @ We2 + be2) (MFMA) -> GF32 f32 + GA bf16 ; stage Ws2
    {
        f32x4 acc = {0.f, 0.f, 0.f, 0.f};
        #pragma unroll
        for (int s = 0; s < 2; ++s) {
            const short8 a = *(const short8*)((const char*)sm + E1A_B + arow*144 + s*64 + akoff);
            const short8 b = *(const short8*)((const char*)sm + WBB_B + ((s*4 + tn4)*64 + l)*16);
            acc = __builtin_amdgcn_mfma_f32_16x16x32_bf16(a, b, acc, 0, 0, 0);
        }
        const float bb = be2[col];
        #pragma unroll
        for (int r = 0; r < 4; ++r) {
            const float sv = siluf(acc[r] + bb);
            sm[GF32_F + col*36 + orow + r] = sv;
            *(unsigned short*)((char*)sm + GA_B + (orow + r)*144 + col*2) = f2bf(sv);
        }
    }
    STAGEFB(WBA_F, fb + FB_WS2, 8192)
    __syncthreads();

    // P4: SO3 GEMM acc[e,k] = sum_i g[e,i]*(g_bf16[e,:] @ 64*Ws1_i[:,k])
    // (R8-proven: B L2->registers, two 8-step banks, compiler-counted vmcnt, no barriers)
    short8 A[2][2];
    #pragma unroll
    for (int et = 0; et < 2; ++et)
        #pragma unroll
        for (int kh = 0; kh < 2; ++kh)
            A[et][kh] = *(const short8*)((const char*)sm + GA_B +
                                         (et*16 + (l & 15))*144 + kh*64 + kg*16);

    float accv[2][4];
    #pragma unroll
    for (int et = 0; et < 2; ++et)
        #pragma unroll
        for (int r = 0; r < 4; ++r) accv[et][r] = 0.0f;

    {
        const short8* Bp = (const short8*)Ws1s;   // frag for step s: Bp[(s*8 + w)*64 + l]
        short8 pA[8], pB[8];

#define LOADBANK(P, BASE) { \
    _Pragma("unroll") \
    for (int j = 0; j < 8; ++j) P[j] = Bp[(((BASE)+j)*8 + w)*64 + l]; \
    __builtin_amdgcn_sched_barrier(0); }
#define USEBANK(P, BASE) { \
    _Pragma("unroll") \
    for (int k = 0; k < 4; ++k) { \
        f32x4 c0 = __builtin_amdgcn_mfma_f32_16x16x32_bf16(A[0][0], P[2*k],   (f32x4){0.f,0.f,0.f,0.f}, 0, 0, 0); \
        f32x4 c1 = __builtin_amdgcn_mfma_f32_16x16x32_bf16(A[1][0], P[2*k],   (f32x4){0.f,0.f,0.f,0.f}, 0, 0, 0); \
        c0 = __builtin_amdgcn_mfma_f32_16x16x32_bf16(A[0][1], P[2*k+1], c0, 0, 0, 0); \
        c1 = __builtin_amdgcn_mfma_f32_16x16x32_bf16(A[1][1], P[2*k+1], c1, 0, 0, 0); \
        const int i_ = (BASE)/2 + k; \
        const f32x4 g0 = *(const f32x4*)&sm[GF32_F + i_*36 + (kg << 2)]; \
        const f32x4 g1 = *(const f32x4*)&sm[GF32_F + i_*36 + 16 + (kg << 2)]; \
        _Pragma("unroll") \
        for (int r = 0; r < 4; ++r) { \
            accv[0][r] = fmaf(g0[r], c0[r], accv[0][r]); \
            accv[1][r] = fmaf(g1[r], c1[r], accv[1][r]); \
        } \
    } }

        LOADBANK(pA, 0)
        LOADBANK(pB, 8)
        #pragma unroll 1
        for (int m = 0; m < 7; ++m) {
            USEBANK(pA, 16*m)
            LOADBANK(pA, 16*m + 16)
            USEBANK(pB, 16*m + 8)
            LOADBANK(pB, 16*m + 24)
        }
        USEBANK(pA, 112)
        USEBANK(pB, 120)
#undef LOADBANK
#undef USEBANK
    }

    // t1 = relu(acc + bs1) -> T1A bf16 A-form [32 e][128 k]
    {
        const int kcol = w*16 + (l & 15);
        const float bk = bs1[kcol];
        #pragma unroll
        for (int et = 0; et < 2; ++et)
            #pragma unroll
            for (int r = 0; r < 4; ++r)
                *(unsigned short*)((char*)sm + T1A_B + (et*16 + (kg<<2) + r)*272 + kcol*2)
                    = f2bf(fmaxf(accv[et][r] + bk, 0.0f));
    }
    STAGEFB(WBB_F, fb + FB_WC1, 4096)
    __syncthreads();

    // P5: ef = t1 @ Ws2 + bs2 (MFMA, K=128) -> global efb (bf16) + EFA bf16
    {
        f32x4 acc = {0.f, 0.f, 0.f, 0.f};
        #pragma unroll
        for (int s = 0; s < 4; ++s) {
            const short8 a = *(const short8*)((const char*)sm + T1A_B + arow*272 + s*64 + akoff);
            const short8 b = *(const short8*)((const char*)sm + WBA_B + ((s*4 + tn4)*64 + l)*16);
            acc = __builtin_amdgcn_mfma_f32_16x16x32_bf16(a, b, acc, 0, 0, 0);
        }
        const float bb = bs2[col];
        #pragma unroll
        for (int r = 0; r < 4; ++r) {
            const unsigned short bv = f2bf(acc[r] + bb);
            efb_out[(size_t)(e0 + orow + r)*64 + col] = bv;
            *(unsigned short*)((char*)sm + EFA_B + (orow + r)*144 + col*2) = bv;
        }
    }
    __syncthreads();

    // P6: v = silu(ef @ Wc1 + bc1) (MFMA) -> V f32 (over dead GF32)
    {
        f32x4 acc = {0.f, 0.f, 0.f, 0.f};
        #pragma unroll
        for (int s = 0; s < 2; ++s) {
            const short8 a = *(const short8*)((const char*)sm + EFA_B + arow*144 + s*64 + akoff);
            const short8 b = *(const short8*)((const char*)sm + WBB_B + ((s*4 + tn4)*64 + l)*16);
            acc = __builtin_amdgcn_mfma_f32_16x16x32_bf16(a, b, acc, 0, 0, 0);
        }
        const float bb = bc1[col];
        #pragma unroll
        for (int r = 0; r < 4; ++r)
            sm[GF32_F + col*36 + orow + r] = siluf(acc[r] + bb);
    }
    __syncthreads();

    // P7: cw = v . Wc2 -> trans
    if (t < 32) {
        float cw = 0.0f;
        for (int f = 0; f < 64; ++f) cw = fmaf(sm[GF32_F + f*36 + t], Wc2[f], cw);
        const int eid = e0 + t;
        trans_out[eid*3 + 0] = s_cd[t]    * cw;
        trans_out[eid*3 + 1] = s_cd[32+t] * cw;
        trans_out[eid*3 + 2] = s_cd[64+t] * cw;
    }
#undef STAGEFB
}

__global__ __launch_bounds__(512, 2)
void egcl_node_kernel(const float* __restrict__ h, const float* __restrict__ coord,
                      const int* __restrict__ ei,
                      const unsigned short* __restrict__ fb,
                      const float* __restrict__ bn1, const float* __restrict__ bn2,
                      const unsigned short* __restrict__ efb, const float* __restrict__ trans,
                      const int* __restrict__ off, const int* __restrict__ eidx,
                      float* __restrict__ out)
{
    __shared__ __attribute__((aligned(16))) float smn[NSM_FLOATS];
    const int t = threadIdx.x;
    const int n0 = blockIdx.x * 32;
    const int l = t & 63, w = t >> 6;
    const int mt = w & 1, tn4 = w >> 1;
    const int kg = l >> 4;
    const int arow = mt * 16 + (l & 15);
    const int akoff = kg * 16;
    const int orow = mt * 16 + (kg << 2);
    const int col = tn4 * 16 + (l & 15);

    // stage Wn1 + Wn2 frags
    for (int i = t*8; i < 10240; i += 4096)
        *(f32x4*)&smn[NW1_F + (i >> 1)] = *(const f32x4*)&fb[FB_WN1 + i];
    for (int i = t*8; i < 5120; i += 4096)
        *(f32x4*)&smn[NW2_F + (i >> 1)] = *(const f32x4*)&fb[FB_WN2 + i];

    // N1 gather: m = [h(64), rel(3), agg(64), 0-pad] bf16 A-form + h_pos f32
    {
        const int nd = t >> 4, fg = t & 15;
        const int gn = n0 + nd;
        const f32x4 hv = *(const f32x4*)&h[(size_t)gn*64 + fg*4];
        #pragma unroll
        for (int u = 0; u < 4; ++u) {
            smn[NHP_F + nd*68 + fg*4 + u] = hv[u];
            *(unsigned short*)((char*)smn + NMA_B + nd*336 + (fg*4+u)*2) = f2bf(hv[u]);
        }
        const int o0 = off[gn], o1 = off[gn + 1];
        float acc[4] = {0.f, 0.f, 0.f, 0.f};
        for (int j = o0; j < o1; ++j) {
            const int e2 = eidx[j];
            const unsigned short* ep = &efb[(size_t)e2*64 + fg*4];
            #pragma unroll
            for (int u = 0; u < 4; ++u) acc[u] += bf2f(ep[u]);
        }
        #pragma unroll
        for (int u = 0; u < 4; ++u)
            *(unsigned short*)((char*)smn + NMA_B + nd*336 + (67+fg*4+u)*2) = f2bf(acc[u]);
    }
    if (t < 32) {
        const int gn = n0 + t;
        const int r = ei[gn], c = ei[EE + gn];   // rel for node n comes from edge n (E==N)
        const float dx = coord[r*3+0] - coord[c*3+0];
        const float dy = coord[r*3+1] - coord[c*3+1];
        const float dz = coord[r*3+2] - coord[c*3+2];
        const float inv = 1.0f / (sqrtf(dx*dx + dy*dy + dz*dz) + 1e-8f);
        const float rl[3] = {dx*inv, dy*inv, dz*inv};
        #pragma unroll
        for (int k = 0; k < 3; ++k) {
            smn[NHP_F + t*68 + 64 + k] = rl[k];
            *(unsigned short*)((char*)smn + NMA_B + t*336 + (64+k)*2) = f2bf(rl[k]);
        }
        // zero-pad bf16 cols 131..159
        #pragma unroll
        for (int cz = 131; cz < 136; ++cz)
            *(unsigned short*)((char*)smn + NMA_B + t*336 + cz*2) = 0;
        const short8 z8 = {0,0,0,0,0,0,0,0};
        #pragma unroll
        for (int ch = 17; ch < 20; ++ch)
            *(short8*)((char*)smn + NMA_B + t*336 + ch*16) = z8;
        // coord_out
        const int o0 = off[gn], o1 = off[gn + 1];
        float nx = 0.f, ny = 0.f, nz = 0.f;
        for (int j = o0; j < o1; ++j) {
            const int e2 = eidx[j];
            nx += trans[e2*3 + 0];
            ny += trans[e2*3 + 1];
            nz += trans[e2*3 + 2];
        }
        const float cnt = fmaxf((float)(o1 - o0), 1.0f);
        out[NN*67 + gn*3 + 0] = coord[gn*3 + 0] + nx / cnt;
        out[NN*67 + gn*3 + 1] = coord[gn*3 + 1] + ny / cnt;
        out[NN*67 + gn*3 + 2] = coord[gn*3 + 2] + nz / cnt;
    }
    __syncthreads();

    // N2: z = silu(m @ Wn1 + bn1) (MFMA, K=160) -> NZA bf16
    {
        f32x4 acc = {0.f, 0.f, 0.f, 0.f};
        #pragma unroll
        for (int s = 0; s < 5; ++s) {
            const short8 a = *(const short8*)((const char*)smn + NMA_B + arow*336 + s*64 + akoff);
            const short8 b = *(const short8*)((const char*)smn + NW1_B + ((s*4 + tn4)*64 + l)*16);
            acc = __builtin_amdgcn_mfma_f32_16x16x32_bf16(a, b, acc, 0, 0, 0);
        }
        const float bb = bn1[col];
        #pragma unroll
        for (int r = 0; r < 4; ++r)
            *(unsigned short*)((char*)smn + NZA_B + (orow + r)*144 + col*2)
                = f2bf(siluf(acc[r] + bb));
    }
    __syncthreads();

    // N3: h_out = h_pos + z @ Wn2 + bn2  (10 tiles of 16 cols over 8 waves; cols >= 67 are pad)
    for (int tid = w; tid < 10; tid += 8) {
        const int mtN = tid & 1, tnN = tid >> 1;
        f32x4 acc = {0.f, 0.f, 0.f, 0.f};
        #pragma unroll
        for (int s = 0; s < 2; ++s) {
            const short8 a = *(const short8*)((const char*)smn + NZA_B + (mtN*16 + (l & 15))*144 + s*64 + akoff);
            const short8 b = *(const short8*)((const char*)smn + NW2_B + ((s*5 + tnN)*64 + l)*16);
            acc = __builtin_amdgcn_mfma_f32_16x16x32_bf16(a, b, acc, 0, 0, 0);
        }
        const int colN = tnN*16 + (l & 15);
        if (colN < 67) {
            const float bb = bn2[colN];
            #pragma unroll
            for (int r = 0; r < 4; ++r) {
                const int row = mtN*16 + (kg << 2) + r;
                out[(size_t)(n0 + row)*67 + colN] = smn[NHP_F + row*68 + colN] + acc[r] + bb;
            }
        }
    }
}

extern "C" void kernel_launch(void* const* d_in, const int* in_sizes, int n_in,
                              void* d_out, int out_size, void* d_ws, size_t ws_size,
                              hipStream_t stream)
{
    (void)in_sizes; (void)n_in; (void)out_size; (void)ws_size;
    const float* h     = (const float*)d_in[0];
    const float* coord = (const float*)d_in[1];
    const int*   ei    = (const int*)d_in[2];
    const float* We1   = (const float*)d_in[3];
    const float* be1   = (const float*)d_in[4];
    const float* We2   = (const float*)d_in[5];
    const float* be2   = (const float*)d_in[6];
    const float* Ws1   = (const float*)d_in[7];
    const float* bs1   = (const float*)d_in[8];
    const float* Ws2   = (const float*)d_in[9];
    const float* bs2   = (const float*)d_in[10];
    const float* Wc1   = (const float*)d_in[11];
    const float* bc1   = (const float*)d_in[12];
    const float* Wc2   = (const float*)d_in[13];
    const float* Wn1   = (const float*)d_in[14];
    const float* bn1   = (const float*)d_in[15];
    const float* Wn2   = (const float*)d_in[16];
    const float* bn2   = (const float*)d_in[17];
    float* ws  = (float*)d_ws;
    float* out = (float*)d_out;

    unsigned short* efb = (unsigned short*)(ws + WS_EFB);
    float* trans = ws + WS_TRANS;
    int* cnti = (int*)(ws + WS_CNTI);
    int* off  = (int*)(ws + WS_OFF);
    int* cur  = (int*)(ws + WS_CUR);
    int* eidx = (int*)(ws + WS_EIDX);
    unsigned short* ws1s = (unsigned short*)(ws + WS_AL);
    unsigned short* fbb  = ws1s + WS1S_ELEMS;

    hipMemsetAsync((void*)cnti, 0, (size_t)NN * sizeof(int), stream);
    prep_all<<<277 + (EE + 255)/256, 256, 0, stream>>>(Ws1, We1, We2, Ws2, Wc1, Wn1, Wn2,
                                                       ws1s, fbb, ei, cnti);
    scan_csr<<<1, 1024, 0, stream>>>(cnti, off, cur);
    fill_csr<<<(EE + 255)/256, 256, 0, stream>>>(ei, cur, eidx);
    egcl_edge_kernel<<<EE/32, 512, 0, stream>>>(h, coord, ei, fbb, be1, be2,
                                                ws1s, bs1, bs2, bc1, Wc2,
                                                efb, trans);
    egcl_node_kernel<<<NN/32, 512, 0, stream>>>(h, coord, ei, fbb, bn1, bn2,
                                                efb, trans, off, eidx, out);
}

// Round 12
// 97.555 us; speedup vs baseline: 3.7195x; 1.0282x over previous
//
#include <hip/hip_runtime.h>

#define NN 20000
#define EE 20000

typedef __attribute__((ext_vector_type(8))) short short8;
typedef __attribute__((ext_vector_type(4))) float f32x4;

// workspace layout (float indices)
#define WS_EFB    0                         // edge_feat bf16 [E][64] = 640000 f32 units
#define WS_TRANS  640000                    // trans f32 [E][3]
#define WS_CNTI   700000                    // int cnt[N]
#define WS_OFF    720000                    // int off[N+1]
#define WS_CUR    740001                    // int cursor[N]
#define WS_EIDX   760001                    // int eidx[E]
#define WS_CORE_END 780001
#define WS_AL     ((WS_CORE_END + 3) & ~3)
#define WS1S_ELEMS (4096*128)               // bf16: swizzled 64*Ws1 (1 MB)
// MLP weight fragment buffers (bf16 elems)
#define FB_WE1 0        // K=129->160, 5 steps : 10240
#define FB_WE2 10240    // K=64, 2 steps       : 4096
#define FB_WS2 14336    // K=128, 4 steps      : 8192
#define FB_WC1 22528    // K=64, 2 steps       : 4096
#define FB_WN1 26624    // K=131->160, 5 steps : 10240
#define FB_WN2 36864    // K=64, 2 steps, 5 tn : 5120
#define FB_ELEMS 41984

// edge-kernel LDS (f32 indices)
#define AIN_F   0        // A_in bf16 [32][336B] ; later T1A bf16 [32][272B]
#define WBA_F   2688     // frag buf A: We1(5120 f32) / Ws2(4096)
#define WBB_F   7808     // frag buf B: We2(2048) / Wc1(2048)
#define E1A_F   9856     // e1 / ef bf16 A-form [32][144B]
#define GF32_F  11008    // g f32 [64][36] ; later v f32
#define GA_F    13312    // g bf16 A-form [32][144B]
#define SM_FLOATS 14464
#define AIN_B   0
#define T1A_B   0
#define WBA_B   (WBA_F*4)
#define WBB_B   (WBB_F*4)
#define E1A_B   (E1A_F*4)
#define EFA_B   (E1A_F*4)
#define GA_B    (GA_F*4)

// node-kernel LDS (f32 indices)
#define NMA_B   0        // m bf16 [32][336B] = 2688 f32
#define NHP_F   2688     // h_pos f32 [32][68] = 2176
#define NW1_F   4864     // Wn1 frags 10240 bf16 = 5120 f32
#define NW2_F   9984     // Wn2 frags 5120 bf16 = 2560 f32
#define NZA_F   12544    // z bf16 A-form [32][144B] = 1152 f32
#define NSM_FLOATS 13696 // 54.8 KB
#define NW1_B   (NW1_F*4)
#define NW2_B   (NW2_F*4)
#define NZA_B   (NZA_F*4)

__device__ __forceinline__ float siluf(float x) {
    return x * (1.0f / (1.0f + __expf(-x)));
}
__device__ __forceinline__ unsigned short f2bf(float f) {
    union { float f; unsigned u; } v; v.f = f;
    return (unsigned short)((v.u + 0x7FFF + ((v.u >> 16) & 1)) >> 16);
}
__device__ __forceinline__ float bf2f(unsigned short x) {
    union { unsigned u; float f; } v; v.u = ((unsigned)x) << 16; return v.f;
}

// ---------- CSR scan (fill is fused into the edge kernel) ----------
__global__ void scan_csr(const int* __restrict__ cnt, int* __restrict__ off,
                         int* __restrict__ cursor) {
    const int t = threadIdx.x;        // 1024 threads, 20 items each
    __shared__ int ps[1024];
    int loc[20];
    int s = 0;
    const int base = t * 20;
    #pragma unroll
    for (int k = 0; k < 20; ++k) {
        const int i = base + k;
        const int c = (i < NN) ? cnt[i] : 0;
        loc[k] = s; s += c;
    }
    ps[t] = s;
    __syncthreads();
    for (int d = 1; d < 1024; d <<= 1) {
        const int v = (t >= d) ? ps[t - d] : 0;
        __syncthreads();
        ps[t] += v;
        __syncthreads();
    }
    const int excl = ps[t] - s;
    #pragma unroll
    for (int k = 0; k < 20; ++k) {
        const int i = base + k;
        if (i < NN) { const int v = excl + loc[k]; off[i] = v; cursor[i] = v; }
    }
    if (t == 1023) off[NN] = ps[1023];
}

// ---------- combined prep: SO3 B swizzle + all MLP frag buffers + degree histogram ----------
__global__ void prep_all(const float* __restrict__ Ws1,
                         const float* __restrict__ We1, const float* __restrict__ We2,
                         const float* __restrict__ Ws2, const float* __restrict__ Wc1,
                         const float* __restrict__ Wn1, const float* __restrict__ Wn2,
                         unsigned short* __restrict__ ws1s, unsigned short* __restrict__ fbb,
                         const int* __restrict__ ei, int* __restrict__ cnt)
{
    const int b = blockIdx.x, t = threadIdx.x;
    if (b < 256) {
        // ws1s[((s*8+tn)*64 + l)*8 + u] = bf16(64*Ws1[(s*32 + 8*(l>>4) + u)][tn*16 + (l&15)])
        const int tid = b * 256 + t;
        const int l = tid & 63, fid = tid >> 6;
        const int s = fid >> 3, tn = fid & 7;
        const int krow = s * 32 + 8 * (l >> 4);
        const int ncol = tn * 16 + (l & 15);
        short8 frag;
        #pragma unroll
        for (int u = 0; u < 8; ++u)
            frag[u] = (short)f2bf(64.0f * Ws1[(krow + u) * 128 + ncol]);
        *(short8*)&ws1s[(size_t)tid * 8] = frag;
    } else if (b < 277) {
        const int idx = (b - 256) * 256 + t;   // 0..5375, valid < 5248
        if (idx < 5248) {
            const float* W; int K, NC, NTN; unsigned short* dst; int local;
            if (idx < 1280)      { W = We1; K = 129; NC = 64; NTN = 4; dst = fbb + FB_WE1; local = idx; }
            else if (idx < 1792) { W = We2; K = 64;  NC = 64; NTN = 4; dst = fbb + FB_WE2; local = idx - 1280; }
            else if (idx < 2816) { W = Ws2; K = 128; NC = 64; NTN = 4; dst = fbb + FB_WS2; local = idx - 1792; }
            else if (idx < 3328) { W = Wc1; K = 64;  NC = 64; NTN = 4; dst = fbb + FB_WC1; local = idx - 2816; }
            else if (idx < 4608) { W = Wn1; K = 131; NC = 64; NTN = 4; dst = fbb + FB_WN1; local = idx - 3328; }
            else                 { W = Wn2; K = 64;  NC = 67; NTN = 5; dst = fbb + FB_WN2; local = idx - 4608; }
            const int per = NTN * 64;
            const int s = local / per, rem = local % per, tn = rem >> 6, ll = rem & 63;
            const int ccol = tn * 16 + (ll & 15), kr0 = s * 32 + 8 * (ll >> 4);
            short8 frag;
            #pragma unroll
            for (int u = 0; u < 8; ++u) {
                const int kr = kr0 + u;
                frag[u] = (kr < K && ccol < NC) ? (short)f2bf(W[kr * NC + ccol]) : (short)0;
            }
            *(short8*)&dst[local * 8] = frag;
        }
    } else {
        const int e = (b - 277) * 256 + t;
        if (e < EE) atomicAdd(&cnt[ei[e]], 1);
    }
}

// __launch_bounds__(512, 2): arg2 = min waves/EU; 512-thr block = 2 waves/EU
// => VGPR cap 128 (the SO3 register banks need ~112; "4" would cap 64 and spill).
__global__ __launch_bounds__(512, 2)
void egcl_edge_kernel(const float* __restrict__ h, const float* __restrict__ coord,
                      const int* __restrict__ ei,
                      const unsigned short* __restrict__ fb,
                      const float* __restrict__ be1, const float* __restrict__ be2,
                      const unsigned short* __restrict__ Ws1s, const float* __restrict__ bs1,
                      const float* __restrict__ bs2, const float* __restrict__ bc1,
                      const float* __restrict__ Wc2,
                      int* __restrict__ cur, int* __restrict__ eidx,
                      unsigned short* __restrict__ efb_out, float* __restrict__ trans_out)
{
    __shared__ __attribute__((aligned(16))) float sm[SM_FLOATS];
    __shared__ int s_row[32], s_col[32];
    __shared__ float s_cd[96], s_rad[32];

    const int t = threadIdx.x;
    const int e0 = blockIdx.x * 32;    // 625 * 32 == 20000
    const int l = t & 63, w = t >> 6;
    const int mt = w & 1, tn4 = w >> 1;
    const int kg = l >> 4;
    const int arow = mt * 16 + (l & 15);
    const int akoff = kg * 16;
    const int orow = mt * 16 + (kg << 2);
    const int col = tn4 * 16 + (l & 15);

#define STAGEFB(DSTF, SRC, NBF16) { \
    const unsigned short* _s = (SRC); \
    for (int i = t*8; i < (NBF16); i += 4096) \
        *(f32x4*)&sm[(DSTF) + (i >> 1)] = *(const f32x4*)&_s[i]; }

    if (t < 32) {
        const int r = ei[e0 + t], c = ei[EE + e0 + t];
        s_row[t] = r; s_col[t] = c;
        const float dx = coord[r*3+0] - coord[c*3+0];
        const float dy = coord[r*3+1] - coord[c*3+1];
        const float dz = coord[r*3+2] - coord[c*3+2];
        s_cd[t] = dx; s_cd[32+t] = dy; s_cd[64+t] = dz;
        s_rad[t] = dx*dx + dy*dy + dz*dz;
        // fused CSR fill (scan_csr ran before this kernel; node runs after)
        const int p = atomicAdd(&cur[r], 1);
        eidx[p] = e0 + t;
    }
    __syncthreads();

    // P1: gather A_in bf16 [32 e][160k pad] + stage We1/We2 frags
    {
        const int ee = t >> 4, fg = t & 15;
        const int r = s_row[ee], c = s_col[ee];
        const float* src = (fg < 8) ? &h[(size_t)r*64 + fg*8] : &h[(size_t)c*64 + (fg-8)*8];
        short8 frag;
        #pragma unroll
        for (int u = 0; u < 8; ++u) frag[u] = (short)f2bf(src[u]);
        *(short8*)((char*)sm + AIN_B + ee*336 + fg*16) = frag;
        if (fg < 5) {
            short8 z = {0,0,0,0,0,0,0,0};
            if (fg == 0) z[0] = (short)f2bf(s_rad[ee]);
            *(short8*)((char*)sm + AIN_B + ee*336 + (16 + fg)*16) = z;
        }
    }
    STAGEFB(WBA_F, fb + FB_WE1, 10240)
    STAGEFB(WBB_F, fb + FB_WE2, 4096)
    __syncthreads();

    // P2: e1 = silu(in @ We1 + be1) (MFMA, K=160) -> E1A bf16
    {
        f32x4 acc = {0.f, 0.f, 0.f, 0.f};
        #pragma unroll
        for (int s = 0; s < 5; ++s) {
            const short8 a = *(const short8*)((const char*)sm + AIN_B + arow*336 + s*64 + akoff);
            const short8 b = *(const short8*)((const char*)sm + WBA_B + ((s*4 + tn4)*64 + l)*16);
            acc = __builtin_amdgcn_mfma_f32_16x16x32_bf16(a, b, acc, 0, 0, 0);
        }
        const float bb = be1[col];
        #pragma unroll
        for (int r = 0; r < 4; ++r)
            *(unsigned short*)((char*)sm + E1A_B + (orow + r)*144 + col*2)
                = f2bf(siluf(acc[r] + bb));
    }
    __syncthreads();

    // P3: g = silu(e1 @ We2 + be2) (MFMA) -> GF32 f32 + GA bf16 ; stage Ws2
    {
        f32x4 acc = {0.f, 0.f, 0.f, 0.f};
        #pragma unroll
        for (int s = 0; s < 2; ++s) {
            const short8 a = *(const short8*)((const char*)sm + E1A_B + arow*144 + s*64 + akoff);
            const short8 b = *(const short8*)((const char*)sm + WBB_B + ((s*4 + tn4)*64 + l)*16);
            acc = __builtin_amdgcn_mfma_f32_16x16x32_bf16(a, b, acc, 0, 0, 0);
        }
        const float bb = be2[col];
        #pragma unroll
        for (int r = 0; r < 4; ++r) {
            const float sv = siluf(acc[r] + bb);
            sm[GF32_F + col*36 + orow + r] = sv;
            *(unsigned short*)((char*)sm + GA_B + (orow + r)*144 + col*2) = f2bf(sv);
        }
    }
    STAGEFB(WBA_F, fb + FB_WS2, 8192)
    __syncthreads();

    // P4: SO3 GEMM acc[e,k] = sum_i g[e,i]*(g_bf16[e,:] @ 64*Ws1_i[:,k])
    // B: L2 -> registers, FOUR banks of 4 steps (64 VGPR total) -> issue->use
    // distance ~3 USEBANKs (~350+ cyc) >= L2 latency; compiler-counted vmcnt,
    // zero barriers, static bank indices.
    short8 A[2][2];
    #pragma unroll
    for (int et = 0; et < 2; ++et)
        #pragma unroll
        for (int kh = 0; kh < 2; ++kh)
            A[et][kh] = *(const short8*)((const char*)sm + GA_B +
                                         (et*16 + (l & 15))*144 + kh*64 + kg*16);

    float accv[2][4];
    #pragma unroll
    for (int et = 0; et < 2; ++et)
        #pragma unroll
        for (int r = 0; r < 4; ++r) accv[et][r] = 0.0f;

    {
        const short8* Bp = (const short8*)Ws1s;   // frag for step s: Bp[(s*8 + w)*64 + l]
        short8 q0[4], q1[4], q2[4], q3[4];

#define LOADBANK(P, G) { \
    _Pragma("unroll") \
    for (int j = 0; j < 4; ++j) P[j] = Bp[((((G)*4 + j)*8 + w)*64 + l)]; \
    __builtin_amdgcn_sched_barrier(0); }
#define USEBANK(P, G) { \
    _Pragma("unroll") \
    for (int kk = 0; kk < 2; ++kk) { \
        f32x4 c0 = __builtin_amdgcn_mfma_f32_16x16x32_bf16(A[0][0], P[2*kk],   (f32x4){0.f,0.f,0.f,0.f}, 0, 0, 0); \
        f32x4 c1 = __builtin_amdgcn_mfma_f32_16x16x32_bf16(A[1][0], P[2*kk],   (f32x4){0.f,0.f,0.f,0.f}, 0, 0, 0); \
        c0 = __builtin_amdgcn_mfma_f32_16x16x32_bf16(A[0][1], P[2*kk+1], c0, 0, 0, 0); \
        c1 = __builtin_amdgcn_mfma_f32_16x16x32_bf16(A[1][1], P[2*kk+1], c1, 0, 0, 0); \
        const int i_ = 2*(G) + kk; \
        const f32x4 g0 = *(const f32x4*)&sm[GF32_F + i_*36 + (kg << 2)]; \
        const f32x4 g1 = *(const f32x4*)&sm[GF32_F + i_*36 + 16 + (kg << 2)]; \
        _Pragma("unroll") \
        for (int r = 0; r < 4; ++r) { \
            accv[0][r] = fmaf(g0[r], c0[r], accv[0][r]); \
            accv[1][r] = fmaf(g1[r], c1[r], accv[1][r]); \
        } \
    } }

        LOADBANK(q0, 0)
        LOADBANK(q1, 1)
        LOADBANK(q2, 2)
        LOADBANK(q3, 3)
        #pragma unroll 1
        for (int m = 0; m < 7; ++m) {
            USEBANK(q0, 4*m)     LOADBANK(q0, 4*m + 4)
            USEBANK(q1, 4*m + 1) LOADBANK(q1, 4*m + 5)
            USEBANK(q2, 4*m + 2) LOADBANK(q2, 4*m + 6)
            USEBANK(q3, 4*m + 3) LOADBANK(q3, 4*m + 7)
        }
        USEBANK(q0, 28)
        USEBANK(q1, 29)
        USEBANK(q2, 30)
        USEBANK(q3, 31)
#undef LOADBANK
#undef USEBANK
    }

    // t1 = relu(acc + bs1) -> T1A bf16 A-form [32 e][128 k]
    {
        const int kcol = w*16 + (l & 15);
        const float bk = bs1[kcol];
        #pragma unroll
        for (int et = 0; et < 2; ++et)
            #pragma unroll
            for (int r = 0; r < 4; ++r)
                *(unsigned short*)((char*)sm + T1A_B + (et*16 + (kg<<2) + r)*272 + kcol*2)
                    = f2bf(fmaxf(accv[et][r] + bk, 0.0f));
    }
    STAGEFB(WBB_F, fb + FB_WC1, 4096)
    __syncthreads();

    // P5: ef = t1 @ Ws2 + bs2 (MFMA, K=128) -> global efb (bf16) + EFA bf16
    {
        f32x4 acc = {0.f, 0.f, 0.f, 0.f};
        #pragma unroll
        for (int s = 0; s < 4; ++s) {
            const short8 a = *(const short8*)((const char*)sm + T1A_B + arow*272 + s*64 + akoff);
            const short8 b = *(const short8*)((const char*)sm + WBA_B + ((s*4 + tn4)*64 + l)*16);
            acc = __builtin_amdgcn_mfma_f32_16x16x32_bf16(a, b, acc, 0, 0, 0);
        }
        const float bb = bs2[col];
        #pragma unroll
        for (int r = 0; r < 4; ++r) {
            const unsigned short bv = f2bf(acc[r] + bb);
            efb_out[(size_t)(e0 + orow + r)*64 + col] = bv;
            *(unsigned short*)((char*)sm + EFA_B + (orow + r)*144 + col*2) = bv;
        }
    }
    __syncthreads();

    // P6: v = silu(ef @ Wc1 + bc1) (MFMA) -> V f32 (over dead GF32)
    {
        f32x4 acc = {0.f, 0.f, 0.f, 0.f};
        #pragma unroll
        for (int s = 0; s < 2; ++s) {
            const short8 a = *(const short8*)((const char*)sm + EFA_B + arow*144 + s*64 + akoff);
            const short8 b = *(const short8*)((const char*)sm + WBB_B + ((s*4 + tn4)*64 + l)*16);
            acc = __builtin_amdgcn_mfma_f32_16x16x32_bf16(a, b, acc, 0, 0, 0);
        }
        const float bb = bc1[col];
        #pragma unroll
        for (int r = 0; r < 4; ++r)
            sm[GF32_F + col*36 + orow + r] = siluf(acc[r] + bb);
    }
    __syncthreads();

    // P7: cw = v . Wc2 -> trans
    if (t < 32) {
        float cw = 0.0f;
        for (int f = 0; f < 64; ++f) cw = fmaf(sm[GF32_F + f*36 + t], Wc2[f], cw);
        const int eid = e0 + t;
        trans_out[eid*3 + 0] = s_cd[t]    * cw;
        trans_out[eid*3 + 1] = s_cd[32+t] * cw;
        trans_out[eid*3 + 2] = s_cd[64+t] * cw;
    }
#undef STAGEFB
}

__global__ __launch_bounds__(512, 2)
void egcl_node_kernel(const float* __restrict__ h, const float* __restrict__ coord,
                      const int* __restrict__ ei,
                      const unsigned short* __restrict__ fb,
                      const float* __restrict__ bn1, const float* __restrict__ bn2,
                      const unsigned short* __restrict__ efb, const float* __restrict__ trans,
                      const int* __restrict__ off, const int* __restrict__ eidx,
                      float* __restrict__ out)
{
    __shared__ __attribute__((aligned(16))) float smn[NSM_FLOATS];
    const int t = threadIdx.x;
    const int n0 = blockIdx.x * 32;
    const int l = t & 63, w = t >> 6;
    const int mt = w & 1, tn4 = w >> 1;
    const int kg = l >> 4;
    const int arow = mt * 16 + (l & 15);
    const int akoff = kg * 16;
    const int orow = mt * 16 + (kg << 2);
    const int col = tn4 * 16 + (l & 15);

    // stage Wn1 + Wn2 frags
    for (int i = t*8; i < 10240; i += 4096)
        *(f32x4*)&smn[NW1_F + (i >> 1)] = *(const f32x4*)&fb[FB_WN1 + i];
    for (int i = t*8; i < 5120; i += 4096)
        *(f32x4*)&smn[NW2_F + (i >> 1)] = *(const f32x4*)&fb[FB_WN2 + i];

    // N1 gather: m = [h(64), rel(3), agg(64), 0-pad] bf16 A-form + h_pos f32
    {
        const int nd = t >> 4, fg = t & 15;
        const int gn = n0 + nd;
        const f32x4 hv = *(const f32x4*)&h[(size_t)gn*64 + fg*4];
        #pragma unroll
        for (int u = 0; u < 4; ++u) {
            smn[NHP_F + nd*68 + fg*4 + u] = hv[u];
            *(unsigned short*)((char*)smn + NMA_B + nd*336 + (fg*4+u)*2) = f2bf(hv[u]);
        }
        const int o0 = off[gn], o1 = off[gn + 1];
        float acc[4] = {0.f, 0.f, 0.f, 0.f};
        for (int j = o0; j < o1; ++j) {
            const int e2 = eidx[j];
            const unsigned short* ep = &efb[(size_t)e2*64 + fg*4];
            #pragma unroll
            for (int u = 0; u < 4; ++u) acc[u] += bf2f(ep[u]);
        }
        #pragma unroll
        for (int u = 0; u < 4; ++u)
            *(unsigned short*)((char*)smn + NMA_B + nd*336 + (67+fg*4+u)*2) = f2bf(acc[u]);
    }
    if (t < 32) {
        const int gn = n0 + t;
        const int r = ei[gn], c = ei[EE + gn];   // rel for node n comes from edge n (E==N)
        const float dx = coord[r*3+0] - coord[c*3+0];
        const float dy = coord[r*3+1] - coord[c*3+1];
        const float dz = coord[r*3+2] - coord[c*3+2];
        const float inv = 1.0f / (sqrtf(dx*dx + dy*dy + dz*dz) + 1e-8f);
        const float rl[3] = {dx*inv, dy*inv, dz*inv};
        #pragma unroll
        for (int k = 0; k < 3; ++k) {
            smn[NHP_F + t*68 + 64 + k] = rl[k];
            *(unsigned short*)((char*)smn + NMA_B + t*336 + (64+k)*2) = f2bf(rl[k]);
        }
        // zero-pad bf16 cols 131..159
        #pragma unroll
        for (int cz = 131; cz < 136; ++cz)
            *(unsigned short*)((char*)smn + NMA_B + t*336 + cz*2) = 0;
        const short8 z8 = {0,0,0,0,0,0,0,0};
        #pragma unroll
        for (int ch = 17; ch < 20; ++ch)
            *(short8*)((char*)smn + NMA_B + t*336 + ch*16) = z8;
        // coord_out
        const int o0 = off[gn], o1 = off[gn + 1];
        float nx = 0.f, ny = 0.f, nz = 0.f;
        for (int j = o0; j < o1; ++j) {
            const int e2 = eidx[j];
            nx += trans[e2*3 + 0];
            ny += trans[e2*3 + 1];
            nz += trans[e2*3 + 2];
        }
        const float cnt = fmaxf((float)(o1 - o0), 1.0f);
        out[NN*67 + gn*3 + 0] = coord[gn*3 + 0] + nx / cnt;
        out[NN*67 + gn*3 + 1] = coord[gn*3 + 1] + ny / cnt;
        out[NN*67 + gn*3 + 2] = coord[gn*3 + 2] + nz / cnt;
    }
    __syncthreads();

    // N2: z = silu(m @ Wn1 + bn1) (MFMA, K=160) -> NZA bf16
    {
        f32x4 acc = {0.f, 0.f, 0.f, 0.f};
        #pragma unroll
        for (int s = 0; s < 5; ++s) {
            const short8 a = *(const short8*)((const char*)smn + NMA_B + arow*336 + s*64 + akoff);
            const short8 b = *(const short8*)((const char*)smn + NW1_B + ((s*4 + tn4)*64 + l)*16);
            acc = __builtin_amdgcn_mfma_f32_16x16x32_bf16(a, b, acc, 0, 0, 0);
        }
        const float bb = bn1[col];
        #pragma unroll
        for (int r = 0; r < 4; ++r)
            *(unsigned short*)((char*)smn + NZA_B + (orow + r)*144 + col*2)
                = f2bf(siluf(acc[r] + bb));
    }
    __syncthreads();

    // N3: h_out = h_pos + z @ Wn2 + bn2  (10 tiles of 16 cols over 8 waves)
    for (int tid = w; tid < 10; tid += 8) {
        const int mtN = tid & 1, tnN = tid >> 1;
        f32x4 acc = {0.f, 0.f, 0.f, 0.f};
        #pragma unroll
        for (int s = 0; s < 2; ++s) {
            const short8 a = *(const short8*)((const char*)smn + NZA_B + (mtN*16 + (l & 15))*144 + s*64 + akoff);
            const short8 b = *(const short8*)((const char*)smn + NW2_B + ((s*5 + tnN)*64 + l)*16);
            acc = __builtin_amdgcn_mfma_f32_16x16x32_bf16(a, b, acc, 0, 0, 0);
        }
        const int colN = tnN*16 + (l & 15);
        if (colN < 67) {
            const float bb = bn2[colN];
            #pragma unroll
            for (int r = 0; r < 4; ++r) {
                const int row = mtN*16 + (kg << 2) + r;
                out[(size_t)(n0 + row)*67 + colN] = smn[NHP_F + row*68 + colN] + acc[r] + bb;
            }
        }
    }
}

extern "C" void kernel_launch(void* const* d_in, const int* in_sizes, int n_in,
                              void* d_out, int out_size, void* d_ws, size_t ws_size,
                              hipStream_t stream)
{
    (void)in_sizes; (void)n_in; (void)out_size; (void)ws_size;
    const float* h     = (const float*)d_in[0];
    const float* coord = (const float*)d_in[1];
    const int*   ei    = (const int*)d_in[2];
    const float* We1   = (const float*)d_in[3];
    const float* be1   = (const float*)d_in[4];
    const float* We2   = (const float*)d_in[5];
    const float* be2   = (const float*)d_in[6];
    const float* Ws1   = (const float*)d_in[7];
    const float* bs1   = (const float*)d_in[8];
    const float* Ws2   = (const float*)d_in[9];
    const float* bs2   = (const float*)d_in[10];
    const float* Wc1   = (const float*)d_in[11];
    const float* bc1   = (const float*)d_in[12];
    const float* Wc2   = (const float*)d_in[13];
    const float* Wn1   = (const float*)d_in[14];
    const float* bn1   = (const float*)d_in[15];
    const float* Wn2   = (const float*)d_in[16];
    const float* bn2   = (const float*)d_in[17];
    float* ws  = (float*)d_ws;
    float* out = (float*)d_out;

    unsigned short* efb = (unsigned short*)(ws + WS_EFB);
    float* trans = ws + WS_TRANS;
    int* cnti = (int*)(ws + WS_CNTI);
    int* off  = (int*)(ws + WS_OFF);
    int* cur  = (int*)(ws + WS_CUR);
    int* eidx = (int*)(ws + WS_EIDX);
    unsigned short* ws1s = (unsigned short*)(ws + WS_AL);
    unsigned short* fbb  = ws1s + WS1S_ELEMS;

    hipMemsetAsync((void*)cnti, 0, (size_t)NN * sizeof(int), stream);
    prep_all<<<277 + (EE + 255)/256, 256, 0, stream>>>(Ws1, We1, We2, Ws2, Wc1, Wn1, Wn2,
                                                       ws1s, fbb, ei, cnti);
    scan_csr<<<1, 1024, 0, stream>>>(cnti, off, cur);
    egcl_edge_kernel<<<EE/32, 512, 0, stream>>>(h, coord, ei, fbb, be1, be2,
                                                ws1s, bs1, bs2, bc1, Wc2,
                                                cur, eidx, efb, trans);
    egcl_node_kernel<<<NN/32, 512, 0, stream>>>(h, coord, ei, fbb, bn1, bn2,
                                                efb, trans, off, eidx, out);
}

// Round 13
// 96.259 us; speedup vs baseline: 3.7695x; 1.0135x over previous
//
#include <hip/hip_runtime.h>

#define NN 20000
#define EE 20000

typedef __attribute__((ext_vector_type(8))) short short8;
typedef __attribute__((ext_vector_type(4))) float f32x4;

// workspace layout (float indices)
#define WS_EFB    0                         // edge_feat bf16 [E][64] = 640000 f32 units
#define WS_TRANS  640000                    // trans f32 [E][3]
#define WS_CNTI   700000                    // int cnt[N]
#define WS_OFF    720000                    // int off[N+1]
#define WS_CUR    740001                    // int cursor[N]
#define WS_EIDX   760001                    // int eidx[E]
#define WS_CORE_END 780001
#define WS_AL     ((WS_CORE_END + 3) & ~3)
#define WS1S_ELEMS (4096*128)               // bf16: swizzled 64*Ws1 (1 MB)
// MLP weight fragment buffers (bf16 elems)
#define FB_WE1 0        // K=129->160, 5 steps : 10240
#define FB_WE2 10240    // K=64, 2 steps       : 4096
#define FB_WS2 14336    // K=128, 4 steps      : 8192
#define FB_WC1 22528    // K=64, 2 steps       : 4096
#define FB_WN1 26624    // K=131->160, 5 steps : 10240
#define FB_WN2 36864    // K=64, 2 steps, 5 tn : 5120
#define FB_ELEMS 41984

// edge-kernel LDS (f32 indices) — 64-edge blocks, no weight staging (frags from L2)
#define AIN_F   0        // A_in bf16 [64][336B] = 5376 f32 ; later T1A bf16 [64][272B]
#define E1A_F   5376     // e1 / ef bf16 A-form [64][144B] = 2304 f32
#define GF32_F  7680     // g f32 [64 i][72] (stride 72) ; later v   = 4608 f32
#define GA_F    12288    // g bf16 A-form [64][144B] = 2304 f32
#define SM_FLOATS 14592  // 58.4 KB
#define AIN_B   0
#define T1A_B   0
#define E1A_B   (E1A_F*4)
#define EFA_B   (E1A_F*4)
#define GA_B    (GA_F*4)

// node-kernel LDS (f32 indices)
#define NMA_B   0        // m bf16 [32][336B] = 2688 f32
#define NHP_F   2688     // h_pos f32 [32][68] = 2176
#define NW1_F   4864     // Wn1 frags 10240 bf16 = 5120 f32
#define NW2_F   9984     // Wn2 frags 5120 bf16 = 2560 f32
#define NZA_F   12544    // z bf16 A-form [32][144B] = 1152 f32
#define NSM_FLOATS 13696 // 54.8 KB
#define NW1_B   (NW1_F*4)
#define NW2_B   (NW2_F*4)
#define NZA_B   (NZA_F*4)

__device__ __forceinline__ float siluf(float x) {
    return x * (1.0f / (1.0f + __expf(-x)));
}
__device__ __forceinline__ unsigned short f2bf(float f) {
    union { float f; unsigned u; } v; v.f = f;
    return (unsigned short)((v.u + 0x7FFF + ((v.u >> 16) & 1)) >> 16);
}
__device__ __forceinline__ float bf2f(unsigned short x) {
    union { unsigned u; float f; } v; v.u = ((unsigned)x) << 16; return v.f;
}

// ---------- CSR scan (fill is fused into the edge kernel) ----------
__global__ void scan_csr(const int* __restrict__ cnt, int* __restrict__ off,
                         int* __restrict__ cursor) {
    const int t = threadIdx.x;        // 1024 threads, 20 items each
    __shared__ int ps[1024];
    int loc[20];
    int s = 0;
    const int base = t * 20;
    #pragma unroll
    for (int k = 0; k < 20; ++k) {
        const int i = base + k;
        const int c = (i < NN) ? cnt[i] : 0;
        loc[k] = s; s += c;
    }
    ps[t] = s;
    __syncthreads();
    for (int d = 1; d < 1024; d <<= 1) {
        const int v = (t >= d) ? ps[t - d] : 0;
        __syncthreads();
        ps[t] += v;
        __syncthreads();
    }
    const int excl = ps[t] - s;
    #pragma unroll
    for (int k = 0; k < 20; ++k) {
        const int i = base + k;
        if (i < NN) { const int v = excl + loc[k]; off[i] = v; cursor[i] = v; }
    }
    if (t == 1023) off[NN] = ps[1023];
}

// ---------- combined prep: SO3 B swizzle + all MLP frag buffers + degree histogram ----------
__global__ void prep_all(const float* __restrict__ Ws1,
                         const float* __restrict__ We1, const float* __restrict__ We2,
                         const float* __restrict__ Ws2, const float* __restrict__ Wc1,
                         const float* __restrict__ Wn1, const float* __restrict__ Wn2,
                         unsigned short* __restrict__ ws1s, unsigned short* __restrict__ fbb,
                         const int* __restrict__ ei, int* __restrict__ cnt)
{
    const int b = blockIdx.x, t = threadIdx.x;
    if (b < 256) {
        // ws1s[((s*8+tn)*64 + l)*8 + u] = bf16(64*Ws1[(s*32 + 8*(l>>4) + u)][tn*16 + (l&15)])
        const int tid = b * 256 + t;
        const int l = tid & 63, fid = tid >> 6;
        const int s = fid >> 3, tn = fid & 7;
        const int krow = s * 32 + 8 * (l >> 4);
        const int ncol = tn * 16 + (l & 15);
        short8 frag;
        #pragma unroll
        for (int u = 0; u < 8; ++u)
            frag[u] = (short)f2bf(64.0f * Ws1[(krow + u) * 128 + ncol]);
        *(short8*)&ws1s[(size_t)tid * 8] = frag;
    } else if (b < 277) {
        const int idx = (b - 256) * 256 + t;   // 0..5375, valid < 5248
        if (idx < 5248) {
            const float* W; int K, NC, NTN; unsigned short* dst; int local;
            if (idx < 1280)      { W = We1; K = 129; NC = 64; NTN = 4; dst = fbb + FB_WE1; local = idx; }
            else if (idx < 1792) { W = We2; K = 64;  NC = 64; NTN = 4; dst = fbb + FB_WE2; local = idx - 1280; }
            else if (idx < 2816) { W = Ws2; K = 128; NC = 64; NTN = 4; dst = fbb + FB_WS2; local = idx - 1792; }
            else if (idx < 3328) { W = Wc1; K = 64;  NC = 64; NTN = 4; dst = fbb + FB_WC1; local = idx - 2816; }
            else if (idx < 4608) { W = Wn1; K = 131; NC = 64; NTN = 4; dst = fbb + FB_WN1; local = idx - 3328; }
            else                 { W = Wn2; K = 64;  NC = 67; NTN = 5; dst = fbb + FB_WN2; local = idx - 4608; }
            const int per = NTN * 64;
            const int s = local / per, rem = local % per, tn = rem >> 6, ll = rem & 63;
            const int ccol = tn * 16 + (ll & 15), kr0 = s * 32 + 8 * (ll >> 4);
            short8 frag;
            #pragma unroll
            for (int u = 0; u < 8; ++u) {
                const int kr = kr0 + u;
                frag[u] = (kr < K && ccol < NC) ? (short)f2bf(W[kr * NC + ccol]) : (short)0;
            }
            *(short8*)&dst[local * 8] = frag;
        }
    } else {
        const int e = (b - 277) * 256 + t;
        if (e < EE) atomicAdd(&cnt[ei[e]], 1);
    }
}

// 64 edges/block: halves the per-block-fixed 1MB Ws1s L2 stream (625->313 MB, the
// measured 12 TB/s binding resource) and fits the whole grid in one residency round.
// __launch_bounds__(512, 2): VGPR cap 128 (GEMM working set ~115).
__global__ __launch_bounds__(512, 2)
void egcl_edge_kernel(const float* __restrict__ h, const float* __restrict__ coord,
                      const int* __restrict__ ei,
                      const unsigned short* __restrict__ fb,
                      const float* __restrict__ be1, const float* __restrict__ be2,
                      const unsigned short* __restrict__ Ws1s, const float* __restrict__ bs1,
                      const float* __restrict__ bs2, const float* __restrict__ bc1,
                      const float* __restrict__ Wc2,
                      int* __restrict__ cur, int* __restrict__ eidx,
                      unsigned short* __restrict__ efb_out, float* __restrict__ trans_out)
{
    __shared__ __attribute__((aligned(16))) float sm[SM_FLOATS];
    __shared__ int s_row[64], s_col[64];
    __shared__ float s_cd[192], s_rad[64];

    const int t = threadIdx.x;
    const int e0 = blockIdx.x * 64;    // 313 blocks; last block: 48 valid edges
    const int l = t & 63, w = t >> 6;
    const int kg = l >> 4;
    const int akoff = kg * 16;
    // MLP tiling: wave w owns row-tile (w&3), col-tiles (w>>2) and (w>>2)+2
    const int mrow = (w & 3) * 16;
    const int arow = mrow + (l & 15);
    const int orow = mrow + (kg << 2);
    const int cA = w >> 2;

    if (t < 64) {
        const int eid = min(e0 + t, EE - 1);
        const int r = ei[eid], c = ei[EE + eid];
        s_row[t] = r; s_col[t] = c;
        const float dx = coord[r*3+0] - coord[c*3+0];
        const float dy = coord[r*3+1] - coord[c*3+1];
        const float dz = coord[r*3+2] - coord[c*3+2];
        s_cd[t] = dx; s_cd[64+t] = dy; s_cd[128+t] = dz;
        s_rad[t] = dx*dx + dy*dy + dz*dz;
        // fused CSR fill (scan_csr ran before this kernel; node runs after)
        if (e0 + t < EE) {
            const int p = atomicAdd(&cur[r], 1);
            eidx[p] = e0 + t;
        }
    }
    __syncthreads();

    // P1: gather A_in bf16 [64 e][160k pad->336B] = [h_row(64), h_col(64), radial, 0]
    {
        const int ee = t >> 3, fg8 = t & 7;
        const int r = s_row[ee], c = s_col[ee];
        short8 fr, fc;
        #pragma unroll
        for (int u = 0; u < 8; ++u) fr[u] = (short)f2bf(h[(size_t)r*64 + fg8*8 + u]);
        #pragma unroll
        for (int u = 0; u < 8; ++u) fc[u] = (short)f2bf(h[(size_t)c*64 + fg8*8 + u]);
        *(short8*)((char*)sm + AIN_B + ee*336 + fg8*16)       = fr;
        *(short8*)((char*)sm + AIN_B + ee*336 + (8+fg8)*16)   = fc;
        if (fg8 < 5) {
            short8 z = {0,0,0,0,0,0,0,0};
            if (fg8 == 0) z[0] = (short)f2bf(s_rad[ee]);
            *(short8*)((char*)sm + AIN_B + ee*336 + (16 + fg8)*16) = z;
        }
    }
    __syncthreads();

    // P2: e1 = silu(in @ We1 + be1) (MFMA, K=160; B-frags direct from L2) -> E1A bf16
    {
        short8 a2[5];
        #pragma unroll
        for (int s = 0; s < 5; ++s)
            a2[s] = *(const short8*)((const char*)sm + AIN_B + arow*336 + s*64 + akoff);
        const short8* Bf = (const short8*)(fb + FB_WE1);
        #pragma unroll
        for (int tt = 0; tt < 2; ++tt) {
            const int tn = cA + tt*2;
            f32x4 acc = {0.f, 0.f, 0.f, 0.f};
            #pragma unroll
            for (int s = 0; s < 5; ++s)
                acc = __builtin_amdgcn_mfma_f32_16x16x32_bf16(a2[s], Bf[(s*4 + tn)*64 + l], acc, 0, 0, 0);
            const int col = tn*16 + (l & 15);
            const float bb = be1[col];
            #pragma unroll
            for (int r = 0; r < 4; ++r)
                *(unsigned short*)((char*)sm + E1A_B + (orow + r)*144 + col*2)
                    = f2bf(siluf(acc[r] + bb));
        }
    }
    __syncthreads();

    // P3: g = silu(e1 @ We2 + be2) (MFMA, K=64) -> GF32 f32 [i][72] + GA bf16 A-form
    {
        short8 a3[2];
        #pragma unroll
        for (int s = 0; s < 2; ++s)
            a3[s] = *(const short8*)((const char*)sm + E1A_B + arow*144 + s*64 + akoff);
        const short8* Bf = (const short8*)(fb + FB_WE2);
        #pragma unroll
        for (int tt = 0; tt < 2; ++tt) {
            const int tn = cA + tt*2;
            f32x4 acc = {0.f, 0.f, 0.f, 0.f};
            #pragma unroll
            for (int s = 0; s < 2; ++s)
                acc = __builtin_amdgcn_mfma_f32_16x16x32_bf16(a3[s], Bf[(s*4 + tn)*64 + l], acc, 0, 0, 0);
            const int col = tn*16 + (l & 15);
            const float bb = be2[col];
            #pragma unroll
            for (int r = 0; r < 4; ++r) {
                const float sv = siluf(acc[r] + bb);
                sm[GF32_F + col*72 + orow + r] = sv;
                *(unsigned short*)((char*)sm + GA_B + (orow + r)*144 + col*2) = f2bf(sv);
            }
        }
    }
    __syncthreads();

    // P4: SO3 GEMM acc[e,k] = sum_i g[e,i]*(g_bf16[e,:] @ 64*Ws1_i[:,k])
    // Wave w owns cols [w*16,+16) x 64 edges (4 et tiles). B: L2 -> registers,
    // 2 banks x 4 steps, compiler-counted vmcnt, zero barriers.
    short8 A[4][2];
    #pragma unroll
    for (int et = 0; et < 4; ++et)
        #pragma unroll
        for (int kh = 0; kh < 2; ++kh)
            A[et][kh] = *(const short8*)((const char*)sm + GA_B +
                                         (et*16 + (l & 15))*144 + kh*64 + kg*16);

    float accv[4][4];
    #pragma unroll
    for (int et = 0; et < 4; ++et)
        #pragma unroll
        for (int r = 0; r < 4; ++r) accv[et][r] = 0.0f;

    {
        const short8* Bp = (const short8*)Ws1s;   // frag for step s: Bp[(s*8 + w)*64 + l]
        short8 q0[4], q1[4];

#define LOADBANK(P, G) { \
    _Pragma("unroll") \
    for (int j = 0; j < 4; ++j) P[j] = Bp[((((G)*4 + j)*8 + w)*64 + l)]; \
    __builtin_amdgcn_sched_barrier(0); }
#define USEBANK(P, G) { \
    _Pragma("unroll") \
    for (int ii = 0; ii < 2; ++ii) { \
        const int i_ = 2*(G) + ii; \
        _Pragma("unroll") \
        for (int et = 0; et < 4; ++et) { \
            f32x4 c = __builtin_amdgcn_mfma_f32_16x16x32_bf16(A[et][0], P[2*ii], (f32x4){0.f,0.f,0.f,0.f}, 0, 0, 0); \
            c = __builtin_amdgcn_mfma_f32_16x16x32_bf16(A[et][1], P[2*ii+1], c, 0, 0, 0); \
            const f32x4 g4 = *(const f32x4*)&sm[GF32_F + i_*72 + et*16 + (kg << 2)]; \
            _Pragma("unroll") \
            for (int r = 0; r < 4; ++r) accv[et][r] = fmaf(g4[r], c[r], accv[et][r]); \
        } \
    } }

        LOADBANK(q0, 0)
        LOADBANK(q1, 1)
        #pragma unroll 1
        for (int m = 0; m < 15; ++m) {
            USEBANK(q0, 2*m)     LOADBANK(q0, 2*m + 2)
            USEBANK(q1, 2*m + 1) LOADBANK(q1, 2*m + 3)
        }
        USEBANK(q0, 30)
        USEBANK(q1, 31)
#undef LOADBANK
#undef USEBANK
    }

    // t1 = relu(acc + bs1) -> T1A bf16 A-form [64 e][128 k] (over dead A_in)
    {
        const int kcol = w*16 + (l & 15);
        const float bk = bs1[kcol];
        #pragma unroll
        for (int et = 0; et < 4; ++et)
            #pragma unroll
            for (int r = 0; r < 4; ++r)
                *(unsigned short*)((char*)sm + T1A_B + (et*16 + (kg<<2) + r)*272 + kcol*2)
                    = f2bf(fmaxf(accv[et][r] + bk, 0.0f));
    }
    __syncthreads();

    // P5: ef = t1 @ Ws2 + bs2 (MFMA, K=128) -> global efb (bf16, guarded) + EFA bf16
    {
        short8 a5[4];
        #pragma unroll
        for (int s = 0; s < 4; ++s)
            a5[s] = *(const short8*)((const char*)sm + T1A_B + arow*272 + s*64 + akoff);
        const short8* Bf = (const short8*)(fb + FB_WS2);
        #pragma unroll
        for (int tt = 0; tt < 2; ++tt) {
            const int tn = cA + tt*2;
            f32x4 acc = {0.f, 0.f, 0.f, 0.f};
            #pragma unroll
            for (int s = 0; s < 4; ++s)
                acc = __builtin_amdgcn_mfma_f32_16x16x32_bf16(a5[s], Bf[(s*4 + tn)*64 + l], acc, 0, 0, 0);
            const int col = tn*16 + (l & 15);
            const float bb = bs2[col];
            #pragma unroll
            for (int r = 0; r < 4; ++r) {
                const unsigned short bv = f2bf(acc[r] + bb);
                if (e0 + orow + r < EE)
                    efb_out[(size_t)(e0 + orow + r)*64 + col] = bv;
                *(unsigned short*)((char*)sm + EFA_B + (orow + r)*144 + col*2) = bv;
            }
        }
    }
    __syncthreads();

    // P6: v = silu(ef @ Wc1 + bc1) (MFMA, K=64) -> V f32 (over dead GF32)
    {
        short8 a6[2];
        #pragma unroll
        for (int s = 0; s < 2; ++s)
            a6[s] = *(const short8*)((const char*)sm + EFA_B + arow*144 + s*64 + akoff);
        const short8* Bf = (const short8*)(fb + FB_WC1);
        #pragma unroll
        for (int tt = 0; tt < 2; ++tt) {
            const int tn = cA + tt*2;
            f32x4 acc = {0.f, 0.f, 0.f, 0.f};
            #pragma unroll
            for (int s = 0; s < 2; ++s)
                acc = __builtin_amdgcn_mfma_f32_16x16x32_bf16(a6[s], Bf[(s*4 + tn)*64 + l], acc, 0, 0, 0);
            const int col = tn*16 + (l & 15);
            const float bb = bc1[col];
            #pragma unroll
            for (int r = 0; r < 4; ++r)
                sm[GF32_F + col*72 + orow + r] = siluf(acc[r] + bb);
        }
    }
    __syncthreads();

    // P7: cw = v . Wc2 -> trans (guarded)
    if (t < 64 && e0 + t < EE) {
        float cw = 0.0f;
        for (int f = 0; f < 64; ++f) cw = fmaf(sm[GF32_F + f*72 + t], Wc2[f], cw);
        const int eid = e0 + t;
        trans_out[eid*3 + 0] = s_cd[t]     * cw;
        trans_out[eid*3 + 1] = s_cd[64+t]  * cw;
        trans_out[eid*3 + 2] = s_cd[128+t] * cw;
    }
}

__global__ __launch_bounds__(512, 2)
void egcl_node_kernel(const float* __restrict__ h, const float* __restrict__ coord,
                      const int* __restrict__ ei,
                      const unsigned short* __restrict__ fb,
                      const float* __restrict__ bn1, const float* __restrict__ bn2,
                      const unsigned short* __restrict__ efb, const float* __restrict__ trans,
                      const int* __restrict__ off, const int* __restrict__ eidx,
                      float* __restrict__ out)
{
    __shared__ __attribute__((aligned(16))) float smn[NSM_FLOATS];
    const int t = threadIdx.x;
    const int n0 = blockIdx.x * 32;
    const int l = t & 63, w = t >> 6;
    const int mt = w & 1, tn4 = w >> 1;
    const int kg = l >> 4;
    const int arow = mt * 16 + (l & 15);
    const int akoff = kg * 16;
    const int orow = mt * 16 + (kg << 2);
    const int col = tn4 * 16 + (l & 15);

    // stage Wn1 + Wn2 frags
    for (int i = t*8; i < 10240; i += 4096)
        *(f32x4*)&smn[NW1_F + (i >> 1)] = *(const f32x4*)&fb[FB_WN1 + i];
    for (int i = t*8; i < 5120; i += 4096)
        *(f32x4*)&smn[NW2_F + (i >> 1)] = *(const f32x4*)&fb[FB_WN2 + i];

    // N1 gather: m = [h(64), rel(3), agg(64), 0-pad] bf16 A-form + h_pos f32
    {
        const int nd = t >> 4, fg = t & 15;
        const int gn = n0 + nd;
        const f32x4 hv = *(const f32x4*)&h[(size_t)gn*64 + fg*4];
        #pragma unroll
        for (int u = 0; u < 4; ++u) {
            smn[NHP_F + nd*68 + fg*4 + u] = hv[u];
            *(unsigned short*)((char*)smn + NMA_B + nd*336 + (fg*4+u)*2) = f2bf(hv[u]);
        }
        const int o0 = off[gn], o1 = off[gn + 1];
        float acc[4] = {0.f, 0.f, 0.f, 0.f};
        for (int j = o0; j < o1; ++j) {
            const int e2 = eidx[j];
            const unsigned short* ep = &efb[(size_t)e2*64 + fg*4];
            #pragma unroll
            for (int u = 0; u < 4; ++u) acc[u] += bf2f(ep[u]);
        }
        #pragma unroll
        for (int u = 0; u < 4; ++u)
            *(unsigned short*)((char*)smn + NMA_B + nd*336 + (67+fg*4+u)*2) = f2bf(acc[u]);
    }
    if (t < 32) {
        const int gn = n0 + t;
        const int r = ei[gn], c = ei[EE + gn];   // rel for node n comes from edge n (E==N)
        const float dx = coord[r*3+0] - coord[c*3+0];
        const float dy = coord[r*3+1] - coord[c*3+1];
        const float dz = coord[r*3+2] - coord[c*3+2];
        const float inv = 1.0f / (sqrtf(dx*dx + dy*dy + dz*dz) + 1e-8f);
        const float rl[3] = {dx*inv, dy*inv, dz*inv};
        #pragma unroll
        for (int k = 0; k < 3; ++k) {
            smn[NHP_F + t*68 + 64 + k] = rl[k];
            *(unsigned short*)((char*)smn + NMA_B + t*336 + (64+k)*2) = f2bf(rl[k]);
        }
        #pragma unroll
        for (int cz = 131; cz < 136; ++cz)
            *(unsigned short*)((char*)smn + NMA_B + t*336 + cz*2) = 0;
        const short8 z8 = {0,0,0,0,0,0,0,0};
        #pragma unroll
        for (int ch = 17; ch < 20; ++ch)
            *(short8*)((char*)smn + NMA_B + t*336 + ch*16) = z8;
        const int o0 = off[gn], o1 = off[gn + 1];
        float nx = 0.f, ny = 0.f, nz = 0.f;
        for (int j = o0; j < o1; ++j) {
            const int e2 = eidx[j];
            nx += trans[e2*3 + 0];
            ny += trans[e2*3 + 1];
            nz += trans[e2*3 + 2];
        }
        const float cnt = fmaxf((float)(o1 - o0), 1.0f);
        out[NN*67 + gn*3 + 0] = coord[gn*3 + 0] + nx / cnt;
        out[NN*67 + gn*3 + 1] = coord[gn*3 + 1] + ny / cnt;
        out[NN*67 + gn*3 + 2] = coord[gn*3 + 2] + nz / cnt;
    }
    __syncthreads();

    // N2: z = silu(m @ Wn1 + bn1) (MFMA, K=160) -> NZA bf16
    {
        f32x4 acc = {0.f, 0.f, 0.f, 0.f};
        #pragma unroll
        for (int s = 0; s < 5; ++s) {
            const short8 a = *(const short8*)((const char*)smn + NMA_B + arow*336 + s*64 + akoff);
            const short8 b = *(const short8*)((const char*)smn + NW1_B + ((s*4 + tn4)*64 + l)*16);
            acc = __builtin_amdgcn_mfma_f32_16x16x32_bf16(a, b, acc, 0, 0, 0);
        }
        const float bb = bn1[col];
        #pragma unroll
        for (int r = 0; r < 4; ++r)
            *(unsigned short*)((char*)smn + NZA_B + (orow + r)*144 + col*2)
                = f2bf(siluf(acc[r] + bb));
    }
    __syncthreads();

    // N3: h_out = h_pos + z @ Wn2 + bn2  (10 tiles of 16 cols over 8 waves)
    for (int tid = w; tid < 10; tid += 8) {
        const int mtN = tid & 1, tnN = tid >> 1;
        f32x4 acc = {0.f, 0.f, 0.f, 0.f};
        #pragma unroll
        for (int s = 0; s < 2; ++s) {
            const short8 a = *(const short8*)((const char*)smn + NZA_B + (mtN*16 + (l & 15))*144 + s*64 + akoff);
            const short8 b = *(const short8*)((const char*)smn + NW2_B + ((s*5 + tnN)*64 + l)*16);
            acc = __builtin_amdgcn_mfma_f32_16x16x32_bf16(a, b, acc, 0, 0, 0);
        }
        const int colN = tnN*16 + (l & 15);
        if (colN < 67) {
            const float bb = bn2[colN];
            #pragma unroll
            for (int r = 0; r < 4; ++r) {
                const int row = mtN*16 + (kg << 2) + r;
                out[(size_t)(n0 + row)*67 + colN] = smn[NHP_F + row*68 + colN] + acc[r] + bb;
            }
        }
    }
}

extern "C" void kernel_launch(void* const* d_in, const int* in_sizes, int n_in,
                              void* d_out, int out_size, void* d_ws, size_t ws_size,
                              hipStream_t stream)
{
    (void)in_sizes; (void)n_in; (void)out_size; (void)ws_size;
    const float* h     = (const float*)d_in[0];
    const float* coord = (const float*)d_in[1];
    const int*   ei    = (const int*)d_in[2];
    const float* We1   = (const float*)d_in[3];
    const float* be1   = (const float*)d_in[4];
    const float* We2   = (const float*)d_in[5];
    const float* be2   = (const float*)d_in[6];
    const float* Ws1   = (const float*)d_in[7];
    const float* bs1   = (const float*)d_in[8];
    const float* Ws2   = (const float*)d_in[9];
    const float* bs2   = (const float*)d_in[10];
    const float* Wc1   = (const float*)d_in[11];
    const float* bc1   = (const float*)d_in[12];
    const float* Wc2   = (const float*)d_in[13];
    const float* Wn1   = (const float*)d_in[14];
    const float* bn1   = (const float*)d_in[15];
    const float* Wn2   = (const float*)d_in[16];
    const float* bn2   = (const float*)d_in[17];
    float* ws  = (float*)d_ws;
    float* out = (float*)d_out;

    unsigned short* efb = (unsigned short*)(ws + WS_EFB);
    float* trans = ws + WS_TRANS;
    int* cnti = (int*)(ws + WS_CNTI);
    int* off  = (int*)(ws + WS_OFF);
    int* cur  = (int*)(ws + WS_CUR);
    int* eidx = (int*)(ws + WS_EIDX);
    unsigned short* ws1s = (unsigned short*)(ws + WS_AL);
    unsigned short* fbb  = ws1s + WS1S_ELEMS;

    hipMemsetAsync((void*)cnti, 0, (size_t)NN * sizeof(int), stream);
    prep_all<<<277 + (EE + 255)/256, 256, 0, stream>>>(Ws1, We1, We2, Ws2, Wc1, Wn1, Wn2,
                                                       ws1s, fbb, ei, cnti);
    scan_csr<<<1, 1024, 0, stream>>>(cnti, off, cur);
    egcl_edge_kernel<<<(EE + 63)/64, 512, 0, stream>>>(h, coord, ei, fbb, be1, be2,
                                                       ws1s, bs1, bs2, bc1, Wc2,
                                                       cur, eidx, efb, trans);
    egcl_node_kernel<<<NN/32, 512, 0, stream>>>(h, coord, ei, fbb, bn1, bn2,
                                                efb, trans, off, eidx, out);
}